// Round 10
// baseline (4341.760 us; speedup 1.0000x reference)
//
#include <hip/hip_runtime.h>
#include <cstdint>

static constexpr int LSEQ = 2048;
static constexpr int NHEAD = 12;

typedef unsigned short u16;
typedef __attribute__((ext_vector_type(8))) short bf16x8;
typedef __attribute__((ext_vector_type(8))) unsigned short u16x8;
typedef __attribute__((ext_vector_type(4))) unsigned short u16x4;
typedef __attribute__((ext_vector_type(4))) float f32x4;

#define MFMA16 __builtin_amdgcn_mfma_f32_16x16x32_bf16

union U8cvt { u16 u[8]; bf16x8 v; u16x8 w; };

__device__ __forceinline__ float silu(float a) { return a / (1.f + __expf(-a)); }

// round-to-nearest-even fp32 -> bf16 hi/lo split
__device__ __forceinline__ void splitf(float x, u16& h, u16& l) {
    uint32_t ux = __float_as_uint(x);
    uint32_t uh = (ux + 0x7fffu + ((ux >> 16) & 1u)) >> 16;
    float hf = __uint_as_float(uh << 16);
    float r = x - hf;
    uint32_t ur = __float_as_uint(r);
    uint32_t ul = (ur + 0x7fffu + ((ur >> 16) & 1u)) >> 16;
    h = (u16)uh; l = (u16)ul;
}

__device__ __forceinline__ void gld16(const void* g, void* l) {
    __builtin_amdgcn_global_load_lds((const __attribute__((address_space(1))) void*)g,
                                     (__attribute__((address_space(3))) void*)l, 16, 0, 0);
}

// bh->XCD affinity decode: wgid = (bh%8) + 8*((bh/8)*NXB + x).
// All blocks of one bh land on xcd = bh%8 (assuming xcd = wgid%8 round-robin)
// -> that XCD's L2 retains the bh's K/V panel across its 80 blocks.
// [R7 verified on attn: FETCH 103->18.5MB. R8 showed this class of swizzle
//  HURTS the GEMMs (B re-streamed per XCD) -> GEMMs keep plain 2D grids.]
__device__ __forceinline__ void bh_decode(int wg, int NXB, int& x, int& bh) {
    const int c8 = wg & 7;
    const int r = wg >> 3;
    x = r % NXB;
    bh = (r / NXB) * 8 + c8;
}

// ---------------- weight pre-split: fp32 [K][Nper] x nsrc -> packed bf16 ---
// ilv=1 (nsrc=2): packed col 2j = s0 col j, 2j+1 = s1 col j (for fused swiglu)
struct SplitEnt { const float* s0; const float* s1; const float* s2;
                  u16* dhi; u16* dlo; int K; int Nper; int nsrc; int bstart; int ilv; };
struct SplitArgs { SplitEnt e[4]; int ne; };

__global__ __launch_bounds__(256)
void wsplit_k(SplitArgs a)
{
    const int blk = blockIdx.x;
    int ti = a.ne - 1;
    for (int i = 1; i < a.ne; ++i) if (blk < a.e[i].bstart) { ti = i - 1; break; }
    const SplitEnt E = a.e[ti];
    const int N = E.Nper * E.nsrc;
    const int u = (blk - E.bstart) * 256 + threadIdx.x;
    const int n = u % N, kb = u / N;
    int which, col;
    if (E.ilv) { which = n & 1; col = n >> 1; }
    else       { which = n / E.Nper; col = n - which * E.Nper; }
    const float* sp = (which == 0 ? E.s0 : which == 1 ? E.s1 : E.s2)
                      + (size_t)(kb * 8) * E.Nper + col;
    U8cvt hh, ll;
#pragma unroll
    for (int j = 0; j < 8; ++j) splitf(sp[(size_t)j * E.Nper], hh.u[j], ll.u[j]);
    *(u16x8*)(E.dhi + (size_t)u * 8) = hh.w;
    *(u16x8*)(E.dlo + (size_t)u * 8) = ll.w;
}

// ================= MFMA split-precision GEMM, packed-weight B ==============
// BM=64 everywhere (R10): 48KB LDS -> 3 blocks/CU residency (vs 2 at 128),
// 2x block count; same K-loop & MFMA order per output -> bit-identical.
// Plain 2D grid (n fastest): concurrent blocks share the A-row band via L3
// and each block's B col-panel L2-fits. [R8: chunked XCD swizzle here HURT.]
// SWI: fused SwiGLU epilogue (B is w1/w3 column-interleaved; writes split
// bf16 silu(a)*g to Shi/Slo with row stride N/2).
template<bool MASK, bool SWI, int BM>
__global__ __launch_bounds__(256)
void gemm_mfma_k(const u16* __restrict__ Ahi, const u16* __restrict__ Alo,
                 const u16* __restrict__ Bhi, const u16* __restrict__ Blo,
                 const float* __restrict__ Res, float* __restrict__ C,
                 u16* __restrict__ Shi, u16* __restrict__ Slo,
                 int N, int K, const int* __restrict__ dS)
{
    constexpr int MFR = BM / 32;             // m-fragments per wave (4 or 2)
    constexpr int AI  = BM / 32;             // A-staging iters (4 or 2)
    const int n0 = blockIdx.x * 128;
    const int m0 = blockIdx.y * BM;
    int S = 1 << 30;
    if (MASK) { S = *dS; if ((m0 & (LSEQ - 1)) >= S) return; }

    __shared__ u16 sm[2 * BM * 64 + 16384];  // A(hi,lo) + B(hi,lo)
    u16* sAhi = sm;
    u16* sAlo = sm + BM * 64;
    u16* sBhi = sm + 2 * BM * 64;
    u16* sBlo = sBhi + 8192;

    const int t = threadIdx.x;
    const int w = t >> 6, lane = t & 63;
    const int wm = (w >> 1) * (BM / 2), wn = (w & 1) * 64;
    const int l15 = lane & 15, l4 = lane >> 4, l7 = lane & 7;

    const f32x4 zf = {0.f, 0.f, 0.f, 0.f};
    f32x4 acc[MFR][4];
#pragma unroll
    for (int i = 0; i < MFR; ++i)
#pragma unroll
        for (int j = 0; j < 4; ++j) acc[i][j] = zf;

    for (int k0 = 0; k0 < K; k0 += 64) {
        __syncthreads();
        // A: pre-swizzled source, linear LDS
#pragma unroll
        for (int i = 0; i < AI; ++i) {
            const int q = i * 256 + t;
            const int mrow = q >> 3;
            const int u = (q & 7) ^ (mrow & 7);
            const size_t goff = (size_t)(m0 + mrow) * K + k0 + u * 8;
            const int lbase = i * 2048 + w * 512;
            gld16(Ahi + goff, (void*)(sAhi + lbase));
            gld16(Alo + goff, (void*)(sAlo + lbase));
        }
        // B: packed k-unit layout, direct linear stage
#pragma unroll
        for (int i = 0; i < 4; ++i) {
            const int q = i * 256 + t;
            const size_t goff = ((size_t)((k0 >> 3) + (q >> 7)) * N + n0 + (q & 127)) * 8;
            const int lbase = i * 2048 + w * 512;
            gld16(Bhi + goff, (void*)(sBhi + lbase));
            gld16(Blo + goff, (void*)(sBlo + lbase));
        }
        __syncthreads();

#pragma unroll
        for (int kk = 0; kk < 2; ++kk) {
            bf16x8 ah[MFR], al[MFR], bh[4], bl[4];
#pragma unroll
            for (int mf = 0; mf < MFR; ++mf) {
                const int row = wm + mf * 16 + l15;
                const int idx = row * 64 + (((kk * 4 + l4) ^ l7) * 8);
                ah[mf] = *(const bf16x8*)(sAhi + idx);
                al[mf] = *(const bf16x8*)(sAlo + idx);
            }
#pragma unroll
            for (int nf = 0; nf < 4; ++nf) {
                const int idx = ((kk * 4 + l4) * 128 + wn + nf * 16 + l15) * 8;
                bh[nf] = *(const bf16x8*)(sBhi + idx);
                bl[nf] = *(const bf16x8*)(sBlo + idx);
            }
#pragma unroll
            for (int mf = 0; mf < MFR; ++mf)
#pragma unroll
                for (int nf = 0; nf < 4; ++nf) {
                    acc[mf][nf] = MFMA16(ah[mf], bh[nf], acc[mf][nf], 0, 0, 0);
                    acc[mf][nf] = MFMA16(ah[mf], bl[nf], acc[mf][nf], 0, 0, 0);
                    acc[mf][nf] = MFMA16(al[mf], bh[nf], acc[mf][nf], 0, 0, 0);
                }
        }
    }

#pragma unroll
    for (int mf = 0; mf < MFR; ++mf) {
#pragma unroll
        for (int r = 0; r < 4; ++r) {
            const int gr = m0 + wm + mf * 16 + l4 * 4 + r;
            if (MASK && (gr & (LSEQ - 1)) >= S) continue;   // pair-uniform (l4,r)
#pragma unroll
            for (int nf = 0; nf < 4; ++nf) {
                const int gc = n0 + wn + nf * 16 + l15;
                float v = acc[mf][nf][r];
                if (SWI) {
                    const float o = __shfl_xor(v, 1);       // partner column
                    if (!(l15 & 1)) {                       // even col = a (w1)
                        const float rr = silu(v) * o;
                        u16 hh, ll; splitf(rr, hh, ll);
                        const size_t bo = (size_t)gr * (N >> 1) + (gc >> 1);
                        Shi[bo] = hh; Slo[bo] = ll;
                    }
                } else {
                    float vv = v;
                    if (Res) vv += Res[(size_t)gr * N + gc];
                    C[(size_t)gr * N + gc] = vv;
                }
            }
        }
    }
}

// ---------------- RMSNorm (float4-vectorized loads/stores, G13) ------------
template<bool F32OUT, bool SPLITOUT>
__global__ __launch_bounds__(256)
void rmsnorm_k(const float* __restrict__ X, const float* __restrict__ w,
               float* __restrict__ OutF, u16* __restrict__ Ohi, u16* __restrict__ Olo,
               int D, const int* __restrict__ dS)
{
    const int row = blockIdx.x;
    if (dS && (row & (LSEQ - 1)) >= *dS) return;
    const float* xr = X + (size_t)row * D;
    const int D4 = D >> 2;
    float ss = 0.f;
    for (int d4 = threadIdx.x; d4 < D4; d4 += 256) {
        const float4 v = *(const float4*)(xr + d4 * 4);
        ss += v.x * v.x + v.y * v.y + v.z * v.z + v.w * v.w;
    }
#pragma unroll
    for (int off = 1; off < 64; off <<= 1) ss += __shfl_xor(ss, off);
    __shared__ float red[4];
    if ((threadIdx.x & 63) == 0) red[threadIdx.x >> 6] = ss;
    __syncthreads();
    const float tot = red[0] + red[1] + red[2] + red[3];
    const float rs = rsqrtf(tot / (float)D + 1e-5f);
    for (int d4 = threadIdx.x; d4 < D4; d4 += 256) {
        const float4 v = *(const float4*)(xr + d4 * 4);
        const float4 wv = *(const float4*)(w + d4 * 4);
        float y[4] = { v.x * rs * wv.x, v.y * rs * wv.y,
                       v.z * rs * wv.z, v.w * rs * wv.w };
        if (F32OUT) {
            float4 o = { y[0], y[1], y[2], y[3] };
            *(float4*)(OutF + (size_t)row * D + d4 * 4) = o;
        }
        if (SPLITOUT) {
            u16x4 hv, lv;
#pragma unroll
            for (int j = 0; j < 4; ++j) { u16 h, l; splitf(y[j], h, l); hv[j] = h; lv[j] = l; }
            *(u16x4*)(Ohi + (size_t)row * D + d4 * 4) = hv;
            *(u16x4*)(Olo + (size_t)row * D + d4 * 4) = lv;
        }
    }
}

// ---------------- RoPE tables ----------------------------------------------
__global__ void ropetab_k(float* c1, float* s1, float* c2, float* s2)
{
    const int idx = blockIdx.x * 256 + threadIdx.x;
    if (idx < 2048 * 32) {
        const int pos = idx >> 5, i = idx & 31;
        const float th = powf(10000.f, -(float)(2 * i) / 64.f);
        const float v = (float)pos * th;
        c1[idx] = cosf(v); s1[idx] = sinf(v);
    }
    const int idx2 = idx - 2048 * 32;
    if (idx2 >= 0 && idx2 < 2048 * 48) {
        const int pos = idx2 / 48, i = idx2 - (idx2 / 48) * 48;
        const float th = powf(10000.f, -(float)(2 * i) / 96.f);
        const float v = (float)pos * th;
        c2[idx2] = cosf(v); s2[idx2] = sinf(v);
    }
}

// ---------------- prep: Q rope in place, K rope->split, V->transposed split
// 1D grid with bh->XCD affinity (NXB=32): K/V writes land in xcd=bh%8's L2.
template<int HD>
__global__ __launch_bounds__(256)
void prep_k(float* __restrict__ QKV, u16* __restrict__ Khi, u16* __restrict__ Klo,
            u16* __restrict__ Vthi, u16* __restrict__ Vtlo,
            const float* __restrict__ ct, const float* __restrict__ st,
            int dm, const int* __restrict__ dS)
{
    constexpr int half = HD / 2;
    int xb, bh;
    bh_decode(blockIdx.x, 32, xb, bh);
    const int s0 = xb * 64;
    if (dS && s0 >= *dS) return;
    const int b = bh / NHEAD, h = bh - b * NHEAD;
    const int qstride = 3 * dm;
    const int t = threadIdx.x;

    // ---- Q/K rope ----
#pragma unroll
    for (int it = 0; it < 64 * half / 256; ++it) {
        const int e = it * 256 + t;
        const int row = e / half, i = e - row * half;
        const int pos = s0 + row;
        const float c = ct[pos * half + i], sn = st[pos * half + i];
        const size_t g = (size_t)(b * LSEQ + pos) * qstride + h * HD + i;
        float x1 = QKV[g], x2 = QKV[g + half];
        QKV[g] = x1 * c - x2 * sn; QKV[g + half] = x2 * c + x1 * sn;
        const size_t gk = g + dm;
        x1 = QKV[gk]; x2 = QKV[gk + half];
        const float k1 = x1 * c - x2 * sn, k2 = x2 * c + x1 * sn;
        const size_t ko = ((size_t)bh * LSEQ + pos) * HD + i;
        u16 hh, ll;
        splitf(k1, hh, ll); Khi[ko] = hh; Klo[ko] = ll;
        splitf(k2, hh, ll); Khi[ko + half] = hh; Klo[ko + half] = ll;
    }

    // ---- V transpose split ----
    __shared__ u16 sh[64][HD], sl[64][HD];
    constexpr int C4 = HD / 4;
#pragma unroll
    for (int it = 0; it < 64 * C4 / 256; ++it) {
        const int q = it * 256 + t;
        const int row = q / C4, c4 = q - row * C4;
        const float4 v = *(const float4*)(QKV + (size_t)(b * LSEQ + s0 + row) * qstride
                                          + 2 * dm + h * HD + c4 * 4);
        u16 hh, ll;
        splitf(v.x, hh, ll); sh[row][c4 * 4 + 0] = hh; sl[row][c4 * 4 + 0] = ll;
        splitf(v.y, hh, ll); sh[row][c4 * 4 + 1] = hh; sl[row][c4 * 4 + 1] = ll;
        splitf(v.z, hh, ll); sh[row][c4 * 4 + 2] = hh; sl[row][c4 * 4 + 2] = ll;
        splitf(v.w, hh, ll); sh[row][c4 * 4 + 3] = hh; sl[row][c4 * 4 + 3] = ll;
    }
    __syncthreads();
    const int s8 = t & 7, d0 = t >> 3;
    for (int d = d0; d < HD; d += 32) {
        U8cvt hh, ll;
#pragma unroll
        for (int j = 0; j < 8; ++j) { hh.u[j] = sh[s8 * 8 + j][d]; ll.u[j] = sl[s8 * 8 + j][d]; }
        const size_t vo = ((size_t)bh * HD + d) * LSEQ + s0 + s8 * 8;
        *(u16x8*)(Vthi + vo) = hh.w;
        *(u16x8*)(Vtlo + vo) = ll.w;
    }
}

// ================= MFMA flash attention v8: uniform k-chunks + XCD affinity
// Causal load-balance: q-tile j (64 rows) is processed by nc(j) blocks, each
// covering a contiguous k-chunk of <=8 tiles:
//   j 0..7: nc=1 (direct O write), 8..15: nc=2, 16..23: nc=3, 24..31: nc=4.
// 80 x-blocks per bh; 1D grid 1920 with bh->XCD affinity: all 80 blocks of a
// bh run on xcd=bh%8 -> its 1MB (HD64) K/V panel stays L2-resident (3 bh x
// 1MB per 4MB L2). [R7 measured: FETCH 103->18.5MB, dur 97->91us]
template<int HD>
__device__ __forceinline__ int kswz(int u, int r) {
    if constexpr (HD == 64) return u ^ (r & 7);
    else return (u & 12) | ((u & 3) ^ (r & 3));
}

__device__ __forceinline__ int slot_of(int j, int c) {
    if (j < 16) return 2 * (j - 8) + c;          // j 8..15
    if (j < 24) return 16 + 3 * (j - 16) + c;    // j 16..23
    return 40 + 4 * (j - 24) + c;                // j 24..31
}

template<int HD>
__global__ __launch_bounds__(256)
void fattn2_k(const float* __restrict__ QKV, const u16* __restrict__ Khi,
              const u16* __restrict__ Klo, const u16* __restrict__ Vthi,
              const u16* __restrict__ Vtlo, u16* __restrict__ Ohi,
              u16* __restrict__ Olo, float* __restrict__ Pacc,
              float* __restrict__ Pml, int dm, float scale,
              const int* __restrict__ dS)
{
    constexpr int BK = 64;
    constexpr int KG8 = HD / 8;
    constexpr int KO = HD / 32;
    constexpr int NFP = HD / 16;
    constexpr float NEG = -3.0e38f;

    int x, bh;
    bh_decode(blockIdx.x, 80, x, bh);            // x 0..79, bh 0..23
    int j, c, nc;
    if (x < 8)       { j = x;                c = 0;            nc = 1; }
    else if (x < 24) { j = 8 + ((x - 8) >> 1);  c = (x - 8) & 1;  nc = 2; }
    else if (x < 48) { j = 16 + (x - 24) / 3;   c = (x - 24) % 3; nc = 3; }
    else             { j = 24 + ((x - 48) >> 2); c = (x - 48) & 3; nc = 4; }
    const int q0 = j * 64;
    int S = 1 << 30;
    if (dS) { S = *dS; if (q0 >= S) return; }
    const int T = j + 1;                         // causal k-tiles for this j
    const int cb = T / nc, crem = T - cb * nc;
    const int cnt = cb + (c < crem ? 1 : 0);
    const int st  = c * cb + (c < crem ? c : crem);
    const int kbeg = st * BK;
    const int kend = (st + cnt) * BK;

    const int b = bh / NHEAD, h = bh - b * NHEAD;
    const int qstride = 3 * dm;

    __shared__ u16 smem[2 * BK * HD + 2 * HD * BK + 4 * 2 * 16 * 64];
    u16* sKhi = smem;
    u16* sKlo = sKhi + BK * HD;
    u16* sVhi = sKlo + BK * HD;
    u16* sVlo = sVhi + HD * BK;
    u16* sP   = sVlo + HD * BK;

    const int t = threadIdx.x;
    const int w = t >> 6, lane = t & 63;
    const int l15 = lane & 15, l4 = lane >> 4;
    u16* sPhi = sP + w * (2 * 16 * 64);
    u16* sPlo = sPhi + 16 * 64;

    const int qbase = q0 + w * 16;

    // ---- Q fragments (scaled + split, registers) ----
    bf16x8 qh[KO], ql[KO];
    {
        const float* qp = QKV + (size_t)(b * LSEQ + qbase + l15) * qstride + h * HD;
#pragma unroll
        for (int ki = 0; ki < KO; ++ki) {
            const float* p = qp + (ki * 4 + l4) * 8;
            U8cvt hh, ll;
#pragma unroll
            for (int jj = 0; jj < 8; ++jj) splitf(p[jj] * scale, hh.u[jj], ll.u[jj]);
            qh[ki] = hh.v; ql[ki] = ll.v;
        }
    }

    float m[4], l[4];
#pragma unroll
    for (int r = 0; r < 4; ++r) { m[r] = NEG; l[r] = 0.f; }
    const f32x4 zf = {0.f, 0.f, 0.f, 0.f};
    f32x4 acc[NFP];
#pragma unroll
    for (int nf = 0; nf < NFP; ++nf) acc[nf] = zf;

    const size_t kbase = (size_t)bh * LSEQ * HD;
    const size_t vbase = (size_t)bh * HD * LSEQ;

    for (int k0 = kbeg; k0 < kend; k0 += BK) {
        __syncthreads();
        // ---- stage K tile (pre-swizzled source, linear LDS) ----
#pragma unroll
        for (int it = 0; it < BK * KG8 / 256; ++it) {
            const int q = it * 256 + t;
            const int r = q / KG8, u = q - r * KG8;
            const int us = kswz<HD>(u, r);
            const size_t go = kbase + (size_t)(k0 + r) * HD + us * 8;
            gld16(Khi + go, (void*)(sKhi + it * 2048 + w * 512));
            gld16(Klo + go, (void*)(sKlo + it * 2048 + w * 512));
        }
        // ---- stage Vt tile ----
#pragma unroll
        for (int it = 0; it < HD * 8 / 256; ++it) {
            const int q = it * 256 + t;
            const int d = q >> 3, u = q & 7;
            const int us = u ^ (d & 7);
            const size_t go = vbase + (size_t)d * LSEQ + k0 + us * 8;
            gld16(Vthi + go, (void*)(sVhi + it * 2048 + w * 512));
            gld16(Vtlo + go, (void*)(sVlo + it * 2048 + w * 512));
        }
        __syncthreads();

        // ---- scores ----
        f32x4 sc[4];
#pragma unroll
        for (int kf = 0; kf < 4; ++kf) sc[kf] = zf;
        __builtin_amdgcn_s_setprio(1);
#pragma unroll
        for (int kf = 0; kf < 4; ++kf) {
            const int row = kf * 16 + l15;
#pragma unroll
            for (int ki = 0; ki < KO; ++ki) {
                const int idx = row * HD + kswz<HD>(ki * 4 + l4, row) * 8;
                const bf16x8 kh = *(const bf16x8*)(sKhi + idx);
                const bf16x8 kl = *(const bf16x8*)(sKlo + idx);
                sc[kf] = MFMA16(qh[ki], kh, sc[kf], 0, 0, 0);
                sc[kf] = MFMA16(qh[ki], kl, sc[kf], 0, 0, 0);
                sc[kf] = MFMA16(ql[ki], kh, sc[kf], 0, 0, 0);
            }
        }
        __builtin_amdgcn_s_setprio(0);

        if (k0 + 63 > qbase) {             // near-diagonal: causal mask
            const int qg = qbase + l4 * 4;
#pragma unroll
            for (int kf = 0; kf < 4; ++kf) {
                const int jc = k0 + kf * 16 + l15;
#pragma unroll
                for (int r = 0; r < 4; ++r)
                    if (jc > qg + r) sc[kf][r] = NEG;
            }
        }

        // ---- online softmax + swizzled P write + rescale ----
        {
            float fac[4];
#pragma unroll
            for (int r = 0; r < 4; ++r) {
                float mx = fmaxf(fmaxf(sc[0][r], sc[1][r]),
                                 fmaxf(sc[2][r], sc[3][r]));
                mx = fmaxf(mx, __shfl_xor(mx, 1));
                mx = fmaxf(mx, __shfl_xor(mx, 2));
                mx = fmaxf(mx, __shfl_xor(mx, 4));
                mx = fmaxf(mx, __shfl_xor(mx, 8));
                const float mn = fmaxf(m[r], mx);
                fac[r] = __expf(m[r] - mn);
                float rs = 0.f;
                float pv[4];
#pragma unroll
                for (int kf = 0; kf < 4; ++kf) { pv[kf] = __expf(sc[kf][r] - mn); rs += pv[kf]; }
                rs += __shfl_xor(rs, 1);
                rs += __shfl_xor(rs, 2);
                rs += __shfl_xor(rs, 4);
                rs += __shfl_xor(rs, 8);
                l[r] = l[r] * fac[r] + rs;
                m[r] = mn;
                const int prow = l4 * 4 + r;
                const int rx = prow & 7;
#pragma unroll
                for (int kf = 0; kf < 4; ++kf) {
                    u16 hh, ll; splitf(pv[kf], hh, ll);
                    const int a = prow * 64 + (((kf * 2 + (l15 >> 3)) ^ rx) * 8) + (l15 & 7);
                    sPhi[a] = hh; sPlo[a] = ll;
                }
            }
#pragma unroll
            for (int nf = 0; nf < NFP; ++nf)
#pragma unroll
                for (int r = 0; r < 4; ++r) acc[nf][r] *= fac[r];
        }

        // ---- PV ----
        bf16x8 ph[2], pl[2];
#pragma unroll
        for (int kk = 0; kk < 2; ++kk) {
            const int a = l15 * 64 + (((kk * 4 + l4) ^ (l15 & 7)) * 8);
            ph[kk] = *(const bf16x8*)(sPhi + a);
            pl[kk] = *(const bf16x8*)(sPlo + a);
        }
        __builtin_amdgcn_s_setprio(1);
#pragma unroll
        for (int nf = 0; nf < NFP; ++nf) {
            const int row = nf * 16 + l15;
#pragma unroll
            for (int kk = 0; kk < 2; ++kk) {
                const int idx = row * 64 + ((kk * 4 + l4) ^ (row & 7)) * 8;
                const bf16x8 vh = *(const bf16x8*)(sVhi + idx);
                const bf16x8 vl = *(const bf16x8*)(sVlo + idx);
                acc[nf] = MFMA16(ph[kk], vh, acc[nf], 0, 0, 0);
                acc[nf] = MFMA16(ph[kk], vl, acc[nf], 0, 0, 0);
                acc[nf] = MFMA16(pl[kk], vh, acc[nf], 0, 0, 0);
            }
        }
        __builtin_amdgcn_s_setprio(0);
    }

    // ---- epilogue ----
    if (nc == 1) {
#pragma unroll
        for (int r = 0; r < 4; ++r) {
            const float rl = 1.f / l[r];
            const size_t ro = (size_t)(b * LSEQ + qbase + l4 * 4 + r) * dm + h * HD;
#pragma unroll
            for (int nf = 0; nf < NFP; ++nf) {
                u16 hh, ll; splitf(acc[nf][r] * rl, hh, ll);
                Ohi[ro + nf * 16 + l15] = hh;
                Olo[ro + nf * 16 + l15] = ll;
            }
        }
    } else {
        const int pi = bh * 72 + slot_of(j, c);
#pragma unroll
        for (int r = 0; r < 4; ++r) {
            const int row = w * 16 + l4 * 4 + r;
            float* pa = Pacc + ((size_t)pi * 64 + row) * HD;
#pragma unroll
            for (int nf = 0; nf < NFP; ++nf)
                pa[nf * 16 + l15] = acc[nf][r];
            if (l15 == 0) {
                Pml[((size_t)pi * 64 + row) * 2 + 0] = m[r];
                Pml[((size_t)pi * 64 + row) * 2 + 1] = l[r];
            }
        }
    }
}

// ---------------- merge nc k-chunk partials -> O ---------------------------
// 1D grid (NXB=24) with same bh->XCD affinity: reads Pacc from the XCD's L2.
template<int HD>
__global__ __launch_bounds__(256)
void attn_merge_k(const float* __restrict__ Pacc, const float* __restrict__ Pml,
                  u16* __restrict__ Ohi, u16* __restrict__ Olo,
                  int dm, const int* __restrict__ dS)
{
    int jx, bh;
    bh_decode(blockIdx.x, 24, jx, bh);
    const int j = 8 + jx;                      // 8..31
    const int q0 = j * 64;
    if (dS && q0 >= *dS) return;
    const int b = bh / NHEAD, h = bh - b * NHEAD;
    const int nc = (j < 16) ? 2 : (j < 24) ? 3 : 4;
    const int pbase = bh * 72 + slot_of(j, 0);

    __shared__ float wsm[4][64], invs[64];
    const int t = threadIdx.x;
    if (t < 64) {
        float m0, m1, m2 = -3.0e38f, m3 = -3.0e38f;
        float l0, l1, l2 = 0.f, l3 = 0.f;
        m0 = Pml[((size_t)(pbase + 0) * 64 + t) * 2];
        l0 = Pml[((size_t)(pbase + 0) * 64 + t) * 2 + 1];
        m1 = Pml[((size_t)(pbase + 1) * 64 + t) * 2];
        l1 = Pml[((size_t)(pbase + 1) * 64 + t) * 2 + 1];
        if (nc > 2) {
            m2 = Pml[((size_t)(pbase + 2) * 64 + t) * 2];
            l2 = Pml[((size_t)(pbase + 2) * 64 + t) * 2 + 1];
        }
        if (nc > 3) {
            m3 = Pml[((size_t)(pbase + 3) * 64 + t) * 2];
            l3 = Pml[((size_t)(pbase + 3) * 64 + t) * 2 + 1];
        }
        const float mm = fmaxf(fmaxf(m0, m1), fmaxf(m2, m3));
        const float w0 = __expf(m0 - mm);
        const float w1 = __expf(m1 - mm);
        const float w2 = (nc > 2) ? __expf(m2 - mm) : 0.f;
        const float w3 = (nc > 3) ? __expf(m3 - mm) : 0.f;
        wsm[0][t] = w0; wsm[1][t] = w1; wsm[2][t] = w2; wsm[3][t] = w3;
        invs[t] = 1.f / (w0 * l0 + w1 * l1 + w2 * l2 + w3 * l3);
    }
    __syncthreads();
    for (int e = t; e < 64 * HD; e += 256) {
        const int row = e / HD, d = e - row * HD;
        float o = wsm[0][row] * Pacc[((size_t)(pbase + 0) * 64 + row) * HD + d]
                + wsm[1][row] * Pacc[((size_t)(pbase + 1) * 64 + row) * HD + d];
        if (nc > 2) o += wsm[2][row] * Pacc[((size_t)(pbase + 2) * 64 + row) * HD + d];
        if (nc > 3) o += wsm[3][row] * Pacc[((size_t)(pbase + 3) * 64 + row) * HD + d];
        o *= invs[row];
        u16 hh, ll; splitf(o, hh, ll);
        const size_t ro = (size_t)(b * LSEQ + q0 + row) * dm + h * HD + d;
        Ohi[ro] = hh; Olo[ro] = ll;
    }
}

// ---------------- Router stage 2 -------------------------------------------
__global__ __launch_bounds__(256)
void router2_k(const float* __restrict__ T, const float* __restrict__ b1,
               const float* __restrict__ w2, const float* __restrict__ b2,
               int* __restrict__ mask)
{
    const int row = blockIdx.x;
    const float* tr = T + (size_t)row * 768;
    float p = 0.f;
    for (int d = threadIdx.x; d < 768; d += 256) {
        const float u = tr[d] + b1[d];
        p += u / (1.f + __expf(-u)) * w2[d];
    }
#pragma unroll
    for (int off = 1; off < 64; off <<= 1) p += __shfl_xor(p, off);
    __shared__ float red[4];
    if ((threadIdx.x & 63) == 0) red[threadIdx.x >> 6] = p;
    __syncthreads();
    if (threadIdx.x == 0) {
        const float logit = red[0] + red[1] + red[2] + red[3] + b2[0];
        mask[row] = ((row & (LSEQ - 1)) == 0 || logit > 0.f) ? 1 : 0;
    }
}

// ---------------- Per-batch inclusive scan + boundaries --------------------
__global__ __launch_bounds__(256)
void scan_k(const int* __restrict__ mask, int* __restrict__ cid,
            int* __restrict__ bnd, int* __restrict__ counts)
{
    const int b = blockIdx.x, t = threadIdx.x;
    const int base = b * LSEQ;
    __shared__ int lds[256];
    int loc[8]; int s = 0;
#pragma unroll
    for (int j = 0; j < 8; ++j) { s += mask[base + t * 8 + j]; loc[j] = s; }
    lds[t] = s;
    __syncthreads();
    for (int off = 1; off < 256; off <<= 1) {
        const int v = (t >= off) ? lds[t - off] : 0;
        __syncthreads();
        lds[t] += v;
        __syncthreads();
    }
    const int excl = lds[t] - s;
#pragma unroll
    for (int j = 0; j < 8; ++j) {
        const int e = t * 8 + j;
        const int c = excl + loc[j];
        cid[base + e] = c - 1;
        if (mask[base + e]) bnd[base + c - 1] = e;
    }
    if (t == 255) counts[b] = lds[255];
}

__global__ void smax_k(const int* __restrict__ counts, int* __restrict__ dS)
{
    if (threadIdx.x == 0 && blockIdx.x == 0) {
        int s = counts[0];
        if (counts[1] > s) s = counts[1];
        dS[0] = s;
    }
}

// ---------------- Gather boundary rows of H -> split bf16 ------------------
__global__ __launch_bounds__(256)
void gather_k(const float* __restrict__ H, const int* __restrict__ bnd,
              const int* __restrict__ counts, u16* __restrict__ Ghi, u16* __restrict__ Glo)
{
    const int s = blockIdx.x, b = blockIdx.y;
    const int cnt = counts[b];
    const size_t go = ((size_t)b * LSEQ + s) * 768;
    if (s < cnt) {
        const float* h = H + ((size_t)b * LSEQ + bnd[b * LSEQ + s]) * 768;
        for (int d = threadIdx.x; d < 768; d += 256) {
            u16 hi, lo; splitf(h[d], hi, lo);
            Ghi[go + d] = hi; Glo[go + d] = lo;
        }
    } else {
        for (int d = threadIdx.x; d < 768; d += 256) { Ghi[go + d] = 0; Glo[go + d] = 0; }
    }
}

// ---------------- y = xp[chunk_id] + h -------------------------------------
__global__ __launch_bounds__(256)
void ybuild_k(const float* __restrict__ XP, const float* __restrict__ H,
              const int* __restrict__ cid, float* __restrict__ Y)
{
    const int row = blockIdx.x;
    const int b = row >> 11;
    const int c = cid[row];
    const float* xp = XP + ((size_t)b * LSEQ + c) * 768;
    const float* h = H + (size_t)row * 768;
    float* y = Y + (size_t)row * 768;
    for (int d = threadIdx.x; d < 768; d += 256) y[d] = xp[d] + h[d];
}

// ===========================================================================
extern "C" void kernel_launch(void* const* d_in, const int* in_sizes, int n_in,
                              void* d_out, int out_size, void* d_ws, size_t ws_size,
                              hipStream_t stream)
{
    auto F = [&](int i) { return (const float*)d_in[i]; };

    struct SW { const float *wq, *wk, *wv, *wo, *w1, *w3, *w2, *ln1, *ln2, *nrm; };
    SW comp, proc, dec;
    const float *rw1, *rb1, *rw2, *rb2, *upw, *dnw;

    const bool sig = (in_sizes[11] == 589824);
    if (!sig) {
        comp = { F(1), F(2), F(3), F(4), F(5), F(6), F(7), F(8), F(9), F(10) };
        proc = { F(11), F(12), F(13), F(14), F(15), F(16), F(17), F(18), F(19), F(20) };
        dec  = { F(21), F(22), F(23), F(24), F(25), F(26), F(27), F(28), F(29), F(30) };
        rw1 = F(31); rb1 = F(32); rw2 = F(33); rb2 = F(34); upw = F(35); dnw = F(36);
    } else {
        comp = { F(1), F(2), F(3), F(4), F(5), F(7), F(6), F(8), F(9), F(10) };
        rw1 = F(11); rb1 = F(12); rw2 = F(13); rb2 = F(14); upw = F(15); dnw = F(16);
        proc = { F(17), F(18), F(19), F(20), F(21), F(23), F(22), F(24), F(25), F(26) };
        dec  = { F(27), F(28), F(29), F(30), F(31), F(33), F(32), F(34), F(35), F(36) };
    }

    // ---- workspace carve (aliased for footprint; liveness-verified) ----
    char* ws = (char*)d_ws;
    size_t off = 0;
    auto alloc = [&](size_t bytes) -> void* {
        void* p = ws + off;
        off = (off + bytes + 255) & ~(size_t)255;
        return p;
    };
    float* X    = (float*)alloc(4096ull * 1152 * 4);
    float* BigF = (float*)alloc(4096ull * 6144 * 4);   // QKV | T13(router) | XP (disjoint lifetimes)
    float* HC   = (float*)alloc(4096ull * 768 * 4);
    u16* HNhi   = (u16*)alloc(4096ull * 1152 * 2);     // also HC-split + gather G
    u16* HNlo   = (u16*)alloc(4096ull * 1152 * 2);
    u16* SWhi   = (u16*)alloc(4096ull * 3072 * 2);     // also attention O (disjoint)
    u16* SWlo   = (u16*)alloc(4096ull * 3072 * 2);
    u16* Khi    = (u16*)alloc(24ull * 2048 * 96 * 2);
    u16* Klo    = (u16*)alloc(24ull * 2048 * 96 * 2);
    u16* Vthi   = (u16*)alloc(24ull * 2048 * 96 * 2);
    u16* Vtlo   = (u16*)alloc(24ull * 2048 * 96 * 2);
    float* Pacc = (float*)alloc(24ull * 72 * 64 * 96 * 4);   // k-chunk partials (72 slots/bh)
    float* Pml  = (float*)alloc(24ull * 72 * 64 * 2 * 4);
    u16* qkvPhi = (u16*)alloc(3981312ull * 2);
    u16* qkvPlo = (u16*)alloc(3981312ull * 2);
    u16* woPhi  = (u16*)alloc(1327104ull * 2);
    u16* woPlo  = (u16*)alloc(1327104ull * 2);
    u16* w13Phi = (u16*)alloc(7077888ull * 2);
    u16* w13Plo = (u16*)alloc(7077888ull * 2);
    u16* w2Phi  = (u16*)alloc(3538944ull * 2);
    u16* w2Plo  = (u16*)alloc(3538944ull * 2);
    u16* rw1Phi = (u16*)alloc(589824ull * 2);
    u16* rw1Plo = (u16*)alloc(589824ull * 2);
    u16* upwPhi = (u16*)alloc(884736ull * 2);
    u16* upwPlo = (u16*)alloc(884736ull * 2);
    u16* dnwPhi = (u16*)alloc(884736ull * 2);
    u16* dnwPlo = (u16*)alloc(884736ull * 2);
    int* mask   = (int*)alloc(4096 * 4);
    int* cid    = (int*)alloc(4096 * 4);
    int* bnd    = (int*)alloc(4096 * 4);
    int* cnts   = (int*)alloc(2 * 4);
    int* dS     = (int*)alloc(256);
    float* c1   = (float*)alloc(2048ull * 32 * 4);
    float* s1   = (float*)alloc(2048ull * 32 * 4);
    float* c2   = (float*)alloc(2048ull * 48 * 4);
    float* s2   = (float*)alloc(2048ull * 48 * 4);

    float* QKV = BigF;              // lives: qkv-gemm .. fattn2
    float* T13 = BigF;              // lives: router gemm only
    float* XP  = BigF;              // lives: down-gemm .. ybuild
    u16* Ohi = SWhi;                // lives: fattn2 .. wo-gemm
    u16* Olo = SWlo;

    hipMemcpyAsync(X, F(0), 4096ull * 768 * 4, hipMemcpyDeviceToDevice, stream);
    ropetab_k<<<640, 256, 0, stream>>>(c1, s1, c2, s2);

    // ---- split router/up/down once ----
    {
        SplitArgs sa{};
        sa.ne = 3;
        sa.e[0] = { rw1, nullptr, nullptr, rw1Phi, rw1Plo, 768, 768, 1, 0, 0 };
        sa.e[1] = { upw, nullptr, nullptr, upwPhi, upwPlo, 768, 1152, 1, 288, 0 };
        sa.e[2] = { dnw, nullptr, nullptr, dnwPhi, dnwPlo, 1152, 768, 1, 720, 0 };
        wsplit_k<<<1152, 256, 0, stream>>>(sa);
    }

    // BM=64 everywhere (R10): 48KB LDS -> 3 blocks/CU, 2x block count.
    auto gemm = [&](const u16* ahi, const u16* alo, const u16* bhi, const u16* blo,
                    const float* res, float* c, int N, int K, const int* ds) {
        if (ds) gemm_mfma_k<true, false, 64><<<dim3(N / 128, 64), 256, 0, stream>>>(
                    ahi, alo, bhi, blo, res, c, nullptr, nullptr, N, K, ds);
        else    gemm_mfma_k<false, false, 64><<<dim3(N / 128, 64), 256, 0, stream>>>(
                    ahi, alo, bhi, blo, res, c, nullptr, nullptr, N, K, nullptr);
    };
    auto gemmswi = [&](const u16* ahi, const u16* alo, const u16* bhi, const u16* blo,
                       u16* shi, u16* slo, int N, int K, const int* ds) {
        if (ds) gemm_mfma_k<true, true, 64><<<dim3(N / 128, 64), 256, 0, stream>>>(
                    ahi, alo, bhi, blo, nullptr, nullptr, shi, slo, N, K, ds);
        else    gemm_mfma_k<false, true, 64><<<dim3(N / 128, 64), 256, 0, stream>>>(
                    ahi, alo, bhi, blo, nullptr, nullptr, shi, slo, N, K, nullptr);
    };

    auto run_layer = [&](const SW& W, int li, int dm, int ff, int hd,
                         const float* ct, const float* st, const int* ds) {
        const size_t wsz = (size_t)dm * dm;
        const float* wq = W.wq + (size_t)li * wsz;
        const float* wk = W.wk + (size_t)li * wsz;
        const float* wv = W.wv + (size_t)li * wsz;
        const float* wo = W.wo + (size_t)li * wsz;
        const float* w1 = W.w1 + (size_t)li * dm * ff;
        const float* w3 = W.w3 + (size_t)li * dm * ff;
        const float* w2 = W.w2 + (size_t)li * ff * dm;
        const float* ln1 = W.ln1 + (size_t)li * dm;
        const float* ln2 = W.ln2 + (size_t)li * dm;
        const float scale = 1.0f / sqrtf((float)hd);

        // pack this layer's weights (w1/w3 column-interleaved for fused swiglu)
        {
            const int b0 = dm * 3 * dm / 2048, b1 = dm * dm / 2048, b2 = dm * 2 * ff / 2048,
                      b3 = ff * dm / 2048;
            SplitArgs sa{};
            sa.ne = 4;
            sa.e[0] = { wq, wk, wv, qkvPhi, qkvPlo, dm, dm, 3, 0, 0 };
            sa.e[1] = { wo, nullptr, nullptr, woPhi, woPlo, dm, dm, 1, b0, 0 };
            sa.e[2] = { w1, w3, nullptr, w13Phi, w13Plo, dm, ff, 2, b0 + b1, 1 };
            sa.e[3] = { w2, nullptr, nullptr, w2Phi, w2Plo, ff, dm, 1, b0 + b1 + b2, 0 };
            wsplit_k<<<b0 + b1 + b2 + b3, 256, 0, stream>>>(sa);
        }

        rmsnorm_k<false, true><<<4096, 256, 0, stream>>>(X, ln1, nullptr, HNhi, HNlo, dm, ds);
        gemm(HNhi, HNlo, qkvPhi, qkvPlo, nullptr, QKV, 3 * dm, dm, ds);
        if (hd == 64) {
            prep_k<64><<<768, 256, 0, stream>>>(QKV, Khi, Klo, Vthi, Vtlo, ct, st, dm, ds);
            fattn2_k<64><<<1920, 256, 0, stream>>>(QKV, Khi, Klo, Vthi, Vtlo, Ohi, Olo, Pacc, Pml, dm, scale, ds);
            attn_merge_k<64><<<576, 256, 0, stream>>>(Pacc, Pml, Ohi, Olo, dm, ds);
        } else {
            prep_k<96><<<768, 256, 0, stream>>>(QKV, Khi, Klo, Vthi, Vtlo, ct, st, dm, ds);
            fattn2_k<96><<<1920, 256, 0, stream>>>(QKV, Khi, Klo, Vthi, Vtlo, Ohi, Olo, Pacc, Pml, dm, scale, ds);
            attn_merge_k<96><<<576, 256, 0, stream>>>(Pacc, Pml, Ohi, Olo, dm, ds);
        }
        gemm(Ohi, Olo, woPhi, woPlo, X, X, dm, dm, ds);
        rmsnorm_k<false, true><<<4096, 256, 0, stream>>>(X, ln2, nullptr, HNhi, HNlo, dm, ds);
        gemmswi(HNhi, HNlo, w13Phi, w13Plo, SWhi, SWlo, 2 * ff, dm, ds);
        gemm(SWhi, SWlo, w2Phi, w2Plo, X, X, dm, ff, ds);
    };

    // ---- compressor trunk (dense) ----
    for (int i = 0; i < 3; ++i) run_layer(comp, i, 768, 2048, 64, c1, s1, nullptr);
    rmsnorm_k<true, true><<<4096, 256, 0, stream>>>(X, comp.nrm, HC, HNhi, HNlo, 768, nullptr);

    // ---- router (HNhi/HNlo hold split HC here) ----
    gemm(HNhi, HNlo, rw1Phi, rw1Plo, nullptr, T13, 768, 768, nullptr);
    router2_k<<<4096, 256, 0, stream>>>(T13, rb1, rw2, rb2, mask);
    scan_k<<<2, 256, 0, stream>>>(mask, cid, bnd, cnts);
    smax_k<<<1, 64, 0, stream>>>(cnts, dS);

    // ---- gather (reuses HNhi/HNlo as G) + up-projection ----
    gather_k<<<dim3(LSEQ, 2), 256, 0, stream>>>(HC, bnd, cnts, HNhi, HNlo);
    gemm(HNhi, HNlo, upwPhi, upwPlo, nullptr, X, 1152, 768, dS);

    // ---- processor stack (padded) ----
    for (int i = 0; i < 6; ++i) run_layer(proc, i, 1152, 3072, 96, c2, s2, dS);
    rmsnorm_k<false, true><<<4096, 256, 0, stream>>>(X, proc.nrm, nullptr, HNhi, HNlo, 1152, dS);
    gemm(HNhi, HNlo, dnwPhi, dnwPlo, nullptr, XP, 768, 1152, dS);

    // ---- scatter back + decoder (dense) ----
    ybuild_k<<<4096, 256, 0, stream>>>(XP, HC, cid, X);
    for (int i = 0; i < 3; ++i) run_layer(dec, i, 768, 2048, 64, c1, s1, nullptr);
    rmsnorm_k<true, false><<<4096, 256, 0, stream>>>(X, dec.nrm, (float*)d_out, nullptr, nullptr, 768, nullptr);
}

// Round 11
// 4250.390 us; speedup vs baseline: 1.0215x; 1.0215x over previous
//
#include <hip/hip_runtime.h>
#include <cstdint>

static constexpr int LSEQ = 2048;
static constexpr int NHEAD = 12;

typedef unsigned short u16;
typedef __attribute__((ext_vector_type(8))) short bf16x8;
typedef __attribute__((ext_vector_type(8))) unsigned short u16x8;
typedef __attribute__((ext_vector_type(4))) unsigned short u16x4;
typedef __attribute__((ext_vector_type(4))) float f32x4;

#define MFMA16 __builtin_amdgcn_mfma_f32_16x16x32_bf16

union U8cvt { u16 u[8]; bf16x8 v; u16x8 w; };

__device__ __forceinline__ float silu(float a) { return a / (1.f + __expf(-a)); }

// round-to-nearest-even fp32 -> bf16 hi/lo split
__device__ __forceinline__ void splitf(float x, u16& h, u16& l) {
    uint32_t ux = __float_as_uint(x);
    uint32_t uh = (ux + 0x7fffu + ((ux >> 16) & 1u)) >> 16;
    float hf = __uint_as_float(uh << 16);
    float r = x - hf;
    uint32_t ur = __float_as_uint(r);
    uint32_t ul = (ur + 0x7fffu + ((ur >> 16) & 1u)) >> 16;
    h = (u16)uh; l = (u16)ul;
}

__device__ __forceinline__ void gld16(const void* g, void* l) {
    __builtin_amdgcn_global_load_lds((const __attribute__((address_space(1))) void*)g,
                                     (__attribute__((address_space(3))) void*)l, 16, 0, 0);
}

// bh->XCD affinity decode: wgid = (bh%8) + 8*((bh/8)*NXB + x).
// All blocks of one bh land on xcd = bh%8 (assuming xcd = wgid%8 round-robin)
// -> that XCD's L2 retains the bh's K/V panel across its 80 blocks.
// [R7 verified on attn: FETCH 103->18.5MB. R8 showed this class of swizzle
//  HURTS the GEMMs (B re-streamed per XCD) -> GEMMs keep plain 2D grids.]
__device__ __forceinline__ void bh_decode(int wg, int NXB, int& x, int& bh) {
    const int c8 = wg & 7;
    const int r = wg >> 3;
    x = r % NXB;
    bh = (r / NXB) * 8 + c8;
}

// ---------------- weight pre-split: fp32 [K][Nper] x nsrc -> packed bf16 ---
// ilv=1 (nsrc=2): packed col 2j = s0 col j, 2j+1 = s1 col j (for fused swiglu)
struct SplitEnt { const float* s0; const float* s1; const float* s2;
                  u16* dhi; u16* dlo; int K; int Nper; int nsrc; int bstart; int ilv; };
struct SplitArgs { SplitEnt e[4]; int ne; };

__global__ __launch_bounds__(256)
void wsplit_k(SplitArgs a)
{
    const int blk = blockIdx.x;
    int ti = a.ne - 1;
    for (int i = 1; i < a.ne; ++i) if (blk < a.e[i].bstart) { ti = i - 1; break; }
    const SplitEnt E = a.e[ti];
    const int N = E.Nper * E.nsrc;
    const int u = (blk - E.bstart) * 256 + threadIdx.x;
    const int n = u % N, kb = u / N;
    int which, col;
    if (E.ilv) { which = n & 1; col = n >> 1; }
    else       { which = n / E.Nper; col = n - which * E.Nper; }
    const float* sp = (which == 0 ? E.s0 : which == 1 ? E.s1 : E.s2)
                      + (size_t)(kb * 8) * E.Nper + col;
    U8cvt hh, ll;
#pragma unroll
    for (int j = 0; j < 8; ++j) splitf(sp[(size_t)j * E.Nper], hh.u[j], ll.u[j]);
    *(u16x8*)(E.dhi + (size_t)u * 8) = hh.w;
    *(u16x8*)(E.dlo + (size_t)u * 8) = ll.w;
}

// ================= MFMA split-precision GEMM, packed-weight B ==============
// BM=64 everywhere (R10): 48KB LDS -> 3 blocks/CU residency, 2x block count.
// Plain 2D grid (n fastest): concurrent blocks share the A-row band via L3
// and each block's B col-panel L2-fits. [R8: chunked XCD swizzle here HURT.]
// SWI: fused SwiGLU epilogue (B is w1/w3 column-interleaved; writes split
// bf16 silu(a)*g to Shi/Slo with row stride N/2).
template<bool MASK, bool SWI, int BM>
__global__ __launch_bounds__(256)
void gemm_mfma_k(const u16* __restrict__ Ahi, const u16* __restrict__ Alo,
                 const u16* __restrict__ Bhi, const u16* __restrict__ Blo,
                 const float* __restrict__ Res, float* __restrict__ C,
                 u16* __restrict__ Shi, u16* __restrict__ Slo,
                 int N, int K, const int* __restrict__ dS)
{
    constexpr int MFR = BM / 32;             // m-fragments per wave (4 or 2)
    constexpr int AI  = BM / 32;             // A-staging iters (4 or 2)
    const int n0 = blockIdx.x * 128;
    const int m0 = blockIdx.y * BM;
    int S = 1 << 30;
    if (MASK) { S = *dS; if ((m0 & (LSEQ - 1)) >= S) return; }

    __shared__ u16 sm[2 * BM * 64 + 16384];  // A(hi,lo) + B(hi,lo)
    u16* sAhi = sm;
    u16* sAlo = sm + BM * 64;
    u16* sBhi = sm + 2 * BM * 64;
    u16* sBlo = sBhi + 8192;

    const int t = threadIdx.x;
    const int w = t >> 6, lane = t & 63;
    const int wm = (w >> 1) * (BM / 2), wn = (w & 1) * 64;
    const int l15 = lane & 15, l4 = lane >> 4, l7 = lane & 7;

    const f32x4 zf = {0.f, 0.f, 0.f, 0.f};
    f32x4 acc[MFR][4];
#pragma unroll
    for (int i = 0; i < MFR; ++i)
#pragma unroll
        for (int j = 0; j < 4; ++j) acc[i][j] = zf;

    for (int k0 = 0; k0 < K; k0 += 64) {
        __syncthreads();
        // A: pre-swizzled source, linear LDS
#pragma unroll
        for (int i = 0; i < AI; ++i) {
            const int q = i * 256 + t;
            const int mrow = q >> 3;
            const int u = (q & 7) ^ (mrow & 7);
            const size_t goff = (size_t)(m0 + mrow) * K + k0 + u * 8;
            const int lbase = i * 2048 + w * 512;
            gld16(Ahi + goff, (void*)(sAhi + lbase));
            gld16(Alo + goff, (void*)(sAlo + lbase));
        }
        // B: packed k-unit layout, direct linear stage
#pragma unroll
        for (int i = 0; i < 4; ++i) {
            const int q = i * 256 + t;
            const size_t goff = ((size_t)((k0 >> 3) + (q >> 7)) * N + n0 + (q & 127)) * 8;
            const int lbase = i * 2048 + w * 512;
            gld16(Bhi + goff, (void*)(sBhi + lbase));
            gld16(Blo + goff, (void*)(sBlo + lbase));
        }
        __syncthreads();

#pragma unroll
        for (int kk = 0; kk < 2; ++kk) {
            bf16x8 ah[MFR], al[MFR], bh[4], bl[4];
#pragma unroll
            for (int mf = 0; mf < MFR; ++mf) {
                const int row = wm + mf * 16 + l15;
                const int idx = row * 64 + (((kk * 4 + l4) ^ l7) * 8);
                ah[mf] = *(const bf16x8*)(sAhi + idx);
                al[mf] = *(const bf16x8*)(sAlo + idx);
            }
#pragma unroll
            for (int nf = 0; nf < 4; ++nf) {
                const int idx = ((kk * 4 + l4) * 128 + wn + nf * 16 + l15) * 8;
                bh[nf] = *(const bf16x8*)(sBhi + idx);
                bl[nf] = *(const bf16x8*)(sBlo + idx);
            }
#pragma unroll
            for (int mf = 0; mf < MFR; ++mf)
#pragma unroll
                for (int nf = 0; nf < 4; ++nf) {
                    acc[mf][nf] = MFMA16(ah[mf], bh[nf], acc[mf][nf], 0, 0, 0);
                    acc[mf][nf] = MFMA16(ah[mf], bl[nf], acc[mf][nf], 0, 0, 0);
                    acc[mf][nf] = MFMA16(al[mf], bh[nf], acc[mf][nf], 0, 0, 0);
                }
        }
    }

#pragma unroll
    for (int mf = 0; mf < MFR; ++mf) {
#pragma unroll
        for (int r = 0; r < 4; ++r) {
            const int gr = m0 + wm + mf * 16 + l4 * 4 + r;
            if (MASK && (gr & (LSEQ - 1)) >= S) continue;   // pair-uniform (l4,r)
#pragma unroll
            for (int nf = 0; nf < 4; ++nf) {
                const int gc = n0 + wn + nf * 16 + l15;
                float v = acc[mf][nf][r];
                if (SWI) {
                    const float o = __shfl_xor(v, 1);       // partner column
                    if (!(l15 & 1)) {                       // even col = a (w1)
                        const float rr = silu(v) * o;
                        u16 hh, ll; splitf(rr, hh, ll);
                        const size_t bo = (size_t)gr * (N >> 1) + (gc >> 1);
                        Shi[bo] = hh; Slo[bo] = ll;
                    }
                } else {
                    float vv = v;
                    if (Res) vv += Res[(size_t)gr * N + gc];
                    C[(size_t)gr * N + gc] = vv;
                }
            }
        }
    }
}

// ---------------- RMSNorm (float4-vectorized loads/stores, G13) ------------
template<bool F32OUT, bool SPLITOUT>
__global__ __launch_bounds__(256)
void rmsnorm_k(const float* __restrict__ X, const float* __restrict__ w,
               float* __restrict__ OutF, u16* __restrict__ Ohi, u16* __restrict__ Olo,
               int D, const int* __restrict__ dS)
{
    const int row = blockIdx.x;
    if (dS && (row & (LSEQ - 1)) >= *dS) return;
    const float* xr = X + (size_t)row * D;
    const int D4 = D >> 2;
    float ss = 0.f;
    for (int d4 = threadIdx.x; d4 < D4; d4 += 256) {
        const float4 v = *(const float4*)(xr + d4 * 4);
        ss += v.x * v.x + v.y * v.y + v.z * v.z + v.w * v.w;
    }
#pragma unroll
    for (int off = 1; off < 64; off <<= 1) ss += __shfl_xor(ss, off);
    __shared__ float red[4];
    if ((threadIdx.x & 63) == 0) red[threadIdx.x >> 6] = ss;
    __syncthreads();
    const float tot = red[0] + red[1] + red[2] + red[3];
    const float rs = rsqrtf(tot / (float)D + 1e-5f);
    for (int d4 = threadIdx.x; d4 < D4; d4 += 256) {
        const float4 v = *(const float4*)(xr + d4 * 4);
        const float4 wv = *(const float4*)(w + d4 * 4);
        float y[4] = { v.x * rs * wv.x, v.y * rs * wv.y,
                       v.z * rs * wv.z, v.w * rs * wv.w };
        if (F32OUT) {
            float4 o = { y[0], y[1], y[2], y[3] };
            *(float4*)(OutF + (size_t)row * D + d4 * 4) = o;
        }
        if (SPLITOUT) {
            u16x4 hv, lv;
#pragma unroll
            for (int j = 0; j < 4; ++j) { u16 h, l; splitf(y[j], h, l); hv[j] = h; lv[j] = l; }
            *(u16x4*)(Ohi + (size_t)row * D + d4 * 4) = hv;
            *(u16x4*)(Olo + (size_t)row * D + d4 * 4) = lv;
        }
    }
}

// ---------------- RoPE tables ----------------------------------------------
__global__ void ropetab_k(float* c1, float* s1, float* c2, float* s2)
{
    const int idx = blockIdx.x * 256 + threadIdx.x;
    if (idx < 2048 * 32) {
        const int pos = idx >> 5, i = idx & 31;
        const float th = powf(10000.f, -(float)(2 * i) / 64.f);
        const float v = (float)pos * th;
        c1[idx] = cosf(v); s1[idx] = sinf(v);
    }
    const int idx2 = idx - 2048 * 32;
    if (idx2 >= 0 && idx2 < 2048 * 48) {
        const int pos = idx2 / 48, i = idx2 - (idx2 / 48) * 48;
        const float th = powf(10000.f, -(float)(2 * i) / 96.f);
        const float v = (float)pos * th;
        c2[idx2] = cosf(v); s2[idx2] = sinf(v);
    }
}

// ---------------- prep: Q rope in place, K rope->split, V->transposed split
// 1D grid with bh->XCD affinity (NXB=32): K/V writes land in xcd=bh%8's L2.
// R11: float4-vectorized rope (4 i-positions/iter) + u16x4 K/LDS stores.
template<int HD>
__global__ __launch_bounds__(256)
void prep_k(float* __restrict__ QKV, u16* __restrict__ Khi, u16* __restrict__ Klo,
            u16* __restrict__ Vthi, u16* __restrict__ Vtlo,
            const float* __restrict__ ct, const float* __restrict__ st,
            int dm, const int* __restrict__ dS)
{
    constexpr int half = HD / 2;
    constexpr int H4 = half / 4;           // 8 @HD64, 12 @HD96
    int xb, bh;
    bh_decode(blockIdx.x, 32, xb, bh);
    const int s0 = xb * 64;
    if (dS && s0 >= *dS) return;
    const int b = bh / NHEAD, h = bh - b * NHEAD;
    const int qstride = 3 * dm;
    const int t = threadIdx.x;

    // ---- Q/K rope (vectorized over 4 consecutive i) ----
    for (int e = t; e < 64 * H4; e += 256) {
        const int row = e / H4, i4 = e - row * H4;
        const int i = i4 * 4;
        const int pos = s0 + row;
        const float4 c  = *(const float4*)(ct + pos * half + i);
        const float4 sn = *(const float4*)(st + pos * half + i);
        const size_t g = (size_t)(b * LSEQ + pos) * qstride + h * HD + i;
        // Q in place
        float4 x1 = *(const float4*)(QKV + g);
        float4 x2 = *(const float4*)(QKV + g + half);
        float4 o1, o2;
        o1.x = x1.x * c.x - x2.x * sn.x;  o2.x = x2.x * c.x + x1.x * sn.x;
        o1.y = x1.y * c.y - x2.y * sn.y;  o2.y = x2.y * c.y + x1.y * sn.y;
        o1.z = x1.z * c.z - x2.z * sn.z;  o2.z = x2.z * c.z + x1.z * sn.z;
        o1.w = x1.w * c.w - x2.w * sn.w;  o2.w = x2.w * c.w + x1.w * sn.w;
        *(float4*)(QKV + g) = o1;
        *(float4*)(QKV + g + half) = o2;
        // K -> split
        const size_t gk = g + dm;
        float4 y1 = *(const float4*)(QKV + gk);
        float4 y2 = *(const float4*)(QKV + gk + half);
        float k1[4] = { y1.x * c.x - y2.x * sn.x, y1.y * c.y - y2.y * sn.y,
                        y1.z * c.z - y2.z * sn.z, y1.w * c.w - y2.w * sn.w };
        float k2[4] = { y2.x * c.x + y1.x * sn.x, y2.y * c.y + y1.y * sn.y,
                        y2.z * c.z + y1.z * sn.z, y2.w * c.w + y1.w * sn.w };
        u16x4 h1, l1, h2, l2;
#pragma unroll
        for (int j = 0; j < 4; ++j) {
            u16 hh, ll;
            splitf(k1[j], hh, ll); h1[j] = hh; l1[j] = ll;
            splitf(k2[j], hh, ll); h2[j] = hh; l2[j] = ll;
        }
        const size_t ko = ((size_t)bh * LSEQ + pos) * HD + i;
        *(u16x4*)(Khi + ko) = h1;        *(u16x4*)(Klo + ko) = l1;
        *(u16x4*)(Khi + ko + half) = h2; *(u16x4*)(Klo + ko + half) = l2;
    }

    // ---- V transpose split ----
    __shared__ u16 sh[64][HD], sl[64][HD];
    constexpr int C4 = HD / 4;
#pragma unroll
    for (int it = 0; it < 64 * C4 / 256; ++it) {
        const int q = it * 256 + t;
        const int row = q / C4, c4 = q - row * C4;
        const float4 v = *(const float4*)(QKV + (size_t)(b * LSEQ + s0 + row) * qstride
                                          + 2 * dm + h * HD + c4 * 4);
        u16x4 hv, lv;
        { u16 hh, ll; splitf(v.x, hh, ll); hv[0] = hh; lv[0] = ll; }
        { u16 hh, ll; splitf(v.y, hh, ll); hv[1] = hh; lv[1] = ll; }
        { u16 hh, ll; splitf(v.z, hh, ll); hv[2] = hh; lv[2] = ll; }
        { u16 hh, ll; splitf(v.w, hh, ll); hv[3] = hh; lv[3] = ll; }
        *(u16x4*)&sh[row][c4 * 4] = hv;
        *(u16x4*)&sl[row][c4 * 4] = lv;
    }
    __syncthreads();
    const int s8 = t & 7, d0 = t >> 3;
    for (int d = d0; d < HD; d += 32) {
        U8cvt hh, ll;
#pragma unroll
        for (int j = 0; j < 8; ++j) { hh.u[j] = sh[s8 * 8 + j][d]; ll.u[j] = sl[s8 * 8 + j][d]; }
        const size_t vo = ((size_t)bh * HD + d) * LSEQ + s0 + s8 * 8;
        *(u16x8*)(Vthi + vo) = hh.w;
        *(u16x8*)(Vtlo + vo) = ll.w;
    }
}

// ================= MFMA flash attention v8: uniform k-chunks + XCD affinity
// Causal load-balance: q-tile j (64 rows) is processed by nc(j) blocks, each
// covering a contiguous k-chunk of <=8 tiles:
//   j 0..7: nc=1 (direct O write), 8..15: nc=2, 16..23: nc=3, 24..31: nc=4.
// 80 x-blocks per bh; 1D grid 1920 with bh->XCD affinity: all 80 blocks of a
// bh run on xcd=bh%8 -> its 1MB (HD64) K/V panel stays L2-resident (3 bh x
// 1MB per 4MB L2). [R7 measured: FETCH 103->18.5MB, dur 97->91us]
template<int HD>
__device__ __forceinline__ int kswz(int u, int r) {
    if constexpr (HD == 64) return u ^ (r & 7);
    else return (u & 12) | ((u & 3) ^ (r & 3));
}

__device__ __forceinline__ int slot_of(int j, int c) {
    if (j < 16) return 2 * (j - 8) + c;          // j 8..15
    if (j < 24) return 16 + 3 * (j - 16) + c;    // j 16..23
    return 40 + 4 * (j - 24) + c;                // j 24..31
}

template<int HD>
__global__ __launch_bounds__(256)
void fattn2_k(const float* __restrict__ QKV, const u16* __restrict__ Khi,
              const u16* __restrict__ Klo, const u16* __restrict__ Vthi,
              const u16* __restrict__ Vtlo, u16* __restrict__ Ohi,
              u16* __restrict__ Olo, float* __restrict__ Pacc,
              float* __restrict__ Pml, int dm, float scale,
              const int* __restrict__ dS)
{
    constexpr int BK = 64;
    constexpr int KG8 = HD / 8;
    constexpr int KO = HD / 32;
    constexpr int NFP = HD / 16;
    constexpr float NEG = -3.0e38f;

    int x, bh;
    bh_decode(blockIdx.x, 80, x, bh);            // x 0..79, bh 0..23
    int j, c, nc;
    if (x < 8)       { j = x;                c = 0;            nc = 1; }
    else if (x < 24) { j = 8 + ((x - 8) >> 1);  c = (x - 8) & 1;  nc = 2; }
    else if (x < 48) { j = 16 + (x - 24) / 3;   c = (x - 24) % 3; nc = 3; }
    else             { j = 24 + ((x - 48) >> 2); c = (x - 48) & 3; nc = 4; }
    const int q0 = j * 64;
    int S = 1 << 30;
    if (dS) { S = *dS; if (q0 >= S) return; }
    const int T = j + 1;                         // causal k-tiles for this j
    const int cb = T / nc, crem = T - cb * nc;
    const int cnt = cb + (c < crem ? 1 : 0);
    const int st  = c * cb + (c < crem ? c : crem);
    const int kbeg = st * BK;
    const int kend = (st + cnt) * BK;

    const int b = bh / NHEAD, h = bh - b * NHEAD;
    const int qstride = 3 * dm;

    __shared__ u16 smem[2 * BK * HD + 2 * HD * BK + 4 * 2 * 16 * 64];
    u16* sKhi = smem;
    u16* sKlo = sKhi + BK * HD;
    u16* sVhi = sKlo + BK * HD;
    u16* sVlo = sVhi + HD * BK;
    u16* sP   = sVlo + HD * BK;

    const int t = threadIdx.x;
    const int w = t >> 6, lane = t & 63;
    const int l15 = lane & 15, l4 = lane >> 4;
    u16* sPhi = sP + w * (2 * 16 * 64);
    u16* sPlo = sPhi + 16 * 64;

    const int qbase = q0 + w * 16;

    // ---- Q fragments (scaled + split, registers) ----
    bf16x8 qh[KO], ql[KO];
    {
        const float* qp = QKV + (size_t)(b * LSEQ + qbase + l15) * qstride + h * HD;
#pragma unroll
        for (int ki = 0; ki < KO; ++ki) {
            const float* p = qp + (ki * 4 + l4) * 8;
            U8cvt hh, ll;
#pragma unroll
            for (int jj = 0; jj < 8; ++jj) splitf(p[jj] * scale, hh.u[jj], ll.u[jj]);
            qh[ki] = hh.v; ql[ki] = ll.v;
        }
    }

    float m[4], l[4];
#pragma unroll
    for (int r = 0; r < 4; ++r) { m[r] = NEG; l[r] = 0.f; }
    const f32x4 zf = {0.f, 0.f, 0.f, 0.f};
    f32x4 acc[NFP];
#pragma unroll
    for (int nf = 0; nf < NFP; ++nf) acc[nf] = zf;

    const size_t kbase = (size_t)bh * LSEQ * HD;
    const size_t vbase = (size_t)bh * HD * LSEQ;

    for (int k0 = kbeg; k0 < kend; k0 += BK) {
        __syncthreads();
        // ---- stage K tile (pre-swizzled source, linear LDS) ----
#pragma unroll
        for (int it = 0; it < BK * KG8 / 256; ++it) {
            const int q = it * 256 + t;
            const int r = q / KG8, u = q - r * KG8;
            const int us = kswz<HD>(u, r);
            const size_t go = kbase + (size_t)(k0 + r) * HD + us * 8;
            gld16(Khi + go, (void*)(sKhi + it * 2048 + w * 512));
            gld16(Klo + go, (void*)(sKlo + it * 2048 + w * 512));
        }
        // ---- stage Vt tile ----
#pragma unroll
        for (int it = 0; it < HD * 8 / 256; ++it) {
            const int q = it * 256 + t;
            const int d = q >> 3, u = q & 7;
            const int us = u ^ (d & 7);
            const size_t go = vbase + (size_t)d * LSEQ + k0 + us * 8;
            gld16(Vthi + go, (void*)(sVhi + it * 2048 + w * 512));
            gld16(Vtlo + go, (void*)(sVlo + it * 2048 + w * 512));
        }
        __syncthreads();

        // ---- scores ----
        f32x4 sc[4];
#pragma unroll
        for (int kf = 0; kf < 4; ++kf) sc[kf] = zf;
        __builtin_amdgcn_s_setprio(1);
#pragma unroll
        for (int kf = 0; kf < 4; ++kf) {
            const int row = kf * 16 + l15;
#pragma unroll
            for (int ki = 0; ki < KO; ++ki) {
                const int idx = row * HD + kswz<HD>(ki * 4 + l4, row) * 8;
                const bf16x8 kh = *(const bf16x8*)(sKhi + idx);
                const bf16x8 kl = *(const bf16x8*)(sKlo + idx);
                sc[kf] = MFMA16(qh[ki], kh, sc[kf], 0, 0, 0);
                sc[kf] = MFMA16(qh[ki], kl, sc[kf], 0, 0, 0);
                sc[kf] = MFMA16(ql[ki], kh, sc[kf], 0, 0, 0);
            }
        }
        __builtin_amdgcn_s_setprio(0);

        if (k0 + 63 > qbase) {             // near-diagonal: causal mask
            const int qg = qbase + l4 * 4;
#pragma unroll
            for (int kf = 0; kf < 4; ++kf) {
                const int jc = k0 + kf * 16 + l15;
#pragma unroll
                for (int r = 0; r < 4; ++r)
                    if (jc > qg + r) sc[kf][r] = NEG;
            }
        }

        // ---- online softmax + swizzled P write + rescale ----
        {
            float fac[4];
#pragma unroll
            for (int r = 0; r < 4; ++r) {
                float mx = fmaxf(fmaxf(sc[0][r], sc[1][r]),
                                 fmaxf(sc[2][r], sc[3][r]));
                mx = fmaxf(mx, __shfl_xor(mx, 1));
                mx = fmaxf(mx, __shfl_xor(mx, 2));
                mx = fmaxf(mx, __shfl_xor(mx, 4));
                mx = fmaxf(mx, __shfl_xor(mx, 8));
                const float mn = fmaxf(m[r], mx);
                fac[r] = __expf(m[r] - mn);
                float rs = 0.f;
                float pv[4];
#pragma unroll
                for (int kf = 0; kf < 4; ++kf) { pv[kf] = __expf(sc[kf][r] - mn); rs += pv[kf]; }
                rs += __shfl_xor(rs, 1);
                rs += __shfl_xor(rs, 2);
                rs += __shfl_xor(rs, 4);
                rs += __shfl_xor(rs, 8);
                l[r] = l[r] * fac[r] + rs;
                m[r] = mn;
                const int prow = l4 * 4 + r;
                const int rx = prow & 7;
#pragma unroll
                for (int kf = 0; kf < 4; ++kf) {
                    u16 hh, ll; splitf(pv[kf], hh, ll);
                    const int a = prow * 64 + (((kf * 2 + (l15 >> 3)) ^ rx) * 8) + (l15 & 7);
                    sPhi[a] = hh; sPlo[a] = ll;
                }
            }
#pragma unroll
            for (int nf = 0; nf < NFP; ++nf)
#pragma unroll
                for (int r = 0; r < 4; ++r) acc[nf][r] *= fac[r];
        }

        // ---- PV ----
        bf16x8 ph[2], pl[2];
#pragma unroll
        for (int kk = 0; kk < 2; ++kk) {
            const int a = l15 * 64 + (((kk * 4 + l4) ^ (l15 & 7)) * 8);
            ph[kk] = *(const bf16x8*)(sPhi + a);
            pl[kk] = *(const bf16x8*)(sPlo + a);
        }
        __builtin_amdgcn_s_setprio(1);
#pragma unroll
        for (int nf = 0; nf < NFP; ++nf) {
            const int row = nf * 16 + l15;
#pragma unroll
            for (int kk = 0; kk < 2; ++kk) {
                const int idx = row * 64 + ((kk * 4 + l4) ^ (row & 7)) * 8;
                const bf16x8 vh = *(const bf16x8*)(sVhi + idx);
                const bf16x8 vl = *(const bf16x8*)(sVlo + idx);
                acc[nf] = MFMA16(ph[kk], vh, acc[nf], 0, 0, 0);
                acc[nf] = MFMA16(ph[kk], vl, acc[nf], 0, 0, 0);
                acc[nf] = MFMA16(pl[kk], vh, acc[nf], 0, 0, 0);
            }
        }
        __builtin_amdgcn_s_setprio(0);
    }

    // ---- epilogue ----
    if (nc == 1) {
#pragma unroll
        for (int r = 0; r < 4; ++r) {
            const float rl = 1.f / l[r];
            const size_t ro = (size_t)(b * LSEQ + qbase + l4 * 4 + r) * dm + h * HD;
#pragma unroll
            for (int nf = 0; nf < NFP; ++nf) {
                u16 hh, ll; splitf(acc[nf][r] * rl, hh, ll);
                Ohi[ro + nf * 16 + l15] = hh;
                Olo[ro + nf * 16 + l15] = ll;
            }
        }
    } else {
        const int pi = bh * 72 + slot_of(j, c);
#pragma unroll
        for (int r = 0; r < 4; ++r) {
            const int row = w * 16 + l4 * 4 + r;
            float* pa = Pacc + ((size_t)pi * 64 + row) * HD;
#pragma unroll
            for (int nf = 0; nf < NFP; ++nf)
                pa[nf * 16 + l15] = acc[nf][r];
            if (l15 == 0) {
                Pml[((size_t)pi * 64 + row) * 2 + 0] = m[r];
                Pml[((size_t)pi * 64 + row) * 2 + 1] = l[r];
            }
        }
    }
}

// ---------------- merge nc k-chunk partials -> O ---------------------------
// 1D grid (NXB=24) with same bh->XCD affinity: reads Pacc from the XCD's L2.
// R11: float4 Pacc reads + u16x4 O writes (same accumulation order).
template<int HD>
__global__ __launch_bounds__(256)
void attn_merge_k(const float* __restrict__ Pacc, const float* __restrict__ Pml,
                  u16* __restrict__ Ohi, u16* __restrict__ Olo,
                  int dm, const int* __restrict__ dS)
{
    int jx, bh;
    bh_decode(blockIdx.x, 24, jx, bh);
    const int j = 8 + jx;                      // 8..31
    const int q0 = j * 64;
    if (dS && q0 >= *dS) return;
    const int b = bh / NHEAD, h = bh - b * NHEAD;
    const int nc = (j < 16) ? 2 : (j < 24) ? 3 : 4;
    const int pbase = bh * 72 + slot_of(j, 0);

    __shared__ float wsm[4][64], invs[64];
    const int t = threadIdx.x;
    if (t < 64) {
        float m0, m1, m2 = -3.0e38f, m3 = -3.0e38f;
        float l0, l1, l2 = 0.f, l3 = 0.f;
        m0 = Pml[((size_t)(pbase + 0) * 64 + t) * 2];
        l0 = Pml[((size_t)(pbase + 0) * 64 + t) * 2 + 1];
        m1 = Pml[((size_t)(pbase + 1) * 64 + t) * 2];
        l1 = Pml[((size_t)(pbase + 1) * 64 + t) * 2 + 1];
        if (nc > 2) {
            m2 = Pml[((size_t)(pbase + 2) * 64 + t) * 2];
            l2 = Pml[((size_t)(pbase + 2) * 64 + t) * 2 + 1];
        }
        if (nc > 3) {
            m3 = Pml[((size_t)(pbase + 3) * 64 + t) * 2];
            l3 = Pml[((size_t)(pbase + 3) * 64 + t) * 2 + 1];
        }
        const float mm = fmaxf(fmaxf(m0, m1), fmaxf(m2, m3));
        const float w0 = __expf(m0 - mm);
        const float w1 = __expf(m1 - mm);
        const float w2 = (nc > 2) ? __expf(m2 - mm) : 0.f;
        const float w3 = (nc > 3) ? __expf(m3 - mm) : 0.f;
        wsm[0][t] = w0; wsm[1][t] = w1; wsm[2][t] = w2; wsm[3][t] = w3;
        invs[t] = 1.f / (w0 * l0 + w1 * l1 + w2 * l2 + w3 * l3);
    }
    __syncthreads();
    constexpr int HD4 = HD / 4;
    for (int e = t; e < 64 * HD4; e += 256) {
        const int row = e / HD4, d4 = e - row * HD4;
        const size_t pb = (size_t)pbase * 64;
        const float4 a0 = *(const float4*)(Pacc + (pb + 0 * 64 + row) * HD + d4 * 4);
        const float4 a1 = *(const float4*)(Pacc + (pb + 1 * 64 + row) * HD + d4 * 4);
        const float w0 = wsm[0][row], w1 = wsm[1][row];
        float o[4] = { w0 * a0.x + w1 * a1.x, w0 * a0.y + w1 * a1.y,
                       w0 * a0.z + w1 * a1.z, w0 * a0.w + w1 * a1.w };
        if (nc > 2) {
            const float4 a2 = *(const float4*)(Pacc + (pb + 2 * 64 + row) * HD + d4 * 4);
            const float w2 = wsm[2][row];
            o[0] += w2 * a2.x; o[1] += w2 * a2.y; o[2] += w2 * a2.z; o[3] += w2 * a2.w;
        }
        if (nc > 3) {
            const float4 a3 = *(const float4*)(Pacc + (pb + 3 * 64 + row) * HD + d4 * 4);
            const float w3 = wsm[3][row];
            o[0] += w3 * a3.x; o[1] += w3 * a3.y; o[2] += w3 * a3.z; o[3] += w3 * a3.w;
        }
        const float iv = invs[row];
        u16x4 hv, lv;
#pragma unroll
        for (int jj = 0; jj < 4; ++jj) { u16 hh, ll; splitf(o[jj] * iv, hh, ll); hv[jj] = hh; lv[jj] = ll; }
        const size_t ro = (size_t)(b * LSEQ + q0 + row) * dm + h * HD + d4 * 4;
        *(u16x4*)(Ohi + ro) = hv;
        *(u16x4*)(Olo + ro) = lv;
    }
}

// ---------------- Router stage 2 -------------------------------------------
__global__ __launch_bounds__(256)
void router2_k(const float* __restrict__ T, const float* __restrict__ b1,
               const float* __restrict__ w2, const float* __restrict__ b2,
               int* __restrict__ mask)
{
    const int row = blockIdx.x;
    const float* tr = T + (size_t)row * 768;
    float p = 0.f;
    for (int d = threadIdx.x; d < 768; d += 256) {
        const float u = tr[d] + b1[d];
        p += u / (1.f + __expf(-u)) * w2[d];
    }
#pragma unroll
    for (int off = 1; off < 64; off <<= 1) p += __shfl_xor(p, off);
    __shared__ float red[4];
    if ((threadIdx.x & 63) == 0) red[threadIdx.x >> 6] = p;
    __syncthreads();
    if (threadIdx.x == 0) {
        const float logit = red[0] + red[1] + red[2] + red[3] + b2[0];
        mask[row] = ((row & (LSEQ - 1)) == 0 || logit > 0.f) ? 1 : 0;
    }
}

// ---------------- Per-batch inclusive scan + boundaries --------------------
__global__ __launch_bounds__(256)
void scan_k(const int* __restrict__ mask, int* __restrict__ cid,
            int* __restrict__ bnd, int* __restrict__ counts)
{
    const int b = blockIdx.x, t = threadIdx.x;
    const int base = b * LSEQ;
    __shared__ int lds[256];
    int loc[8]; int s = 0;
#pragma unroll
    for (int j = 0; j < 8; ++j) { s += mask[base + t * 8 + j]; loc[j] = s; }
    lds[t] = s;
    __syncthreads();
    for (int off = 1; off < 256; off <<= 1) {
        const int v = (t >= off) ? lds[t - off] : 0;
        __syncthreads();
        lds[t] += v;
        __syncthreads();
    }
    const int excl = lds[t] - s;
#pragma unroll
    for (int j = 0; j < 8; ++j) {
        const int e = t * 8 + j;
        const int c = excl + loc[j];
        cid[base + e] = c - 1;
        if (mask[base + e]) bnd[base + c - 1] = e;
    }
    if (t == 255) counts[b] = lds[255];
}

__global__ void smax_k(const int* __restrict__ counts, int* __restrict__ dS)
{
    if (threadIdx.x == 0 && blockIdx.x == 0) {
        int s = counts[0];
        if (counts[1] > s) s = counts[1];
        dS[0] = s;
    }
}

// ---------------- Gather boundary rows of H -> split bf16 ------------------
__global__ __launch_bounds__(256)
void gather_k(const float* __restrict__ H, const int* __restrict__ bnd,
              const int* __restrict__ counts, u16* __restrict__ Ghi, u16* __restrict__ Glo)
{
    const int s = blockIdx.x, b = blockIdx.y;
    const int cnt = counts[b];
    const size_t go = ((size_t)b * LSEQ + s) * 768;
    if (s < cnt) {
        const float* h = H + ((size_t)b * LSEQ + bnd[b * LSEQ + s]) * 768;
        for (int d = threadIdx.x; d < 768; d += 256) {
            u16 hi, lo; splitf(h[d], hi, lo);
            Ghi[go + d] = hi; Glo[go + d] = lo;
        }
    } else {
        for (int d = threadIdx.x; d < 768; d += 256) { Ghi[go + d] = 0; Glo[go + d] = 0; }
    }
}

// ---------------- y = xp[chunk_id] + h -------------------------------------
__global__ __launch_bounds__(256)
void ybuild_k(const float* __restrict__ XP, const float* __restrict__ H,
              const int* __restrict__ cid, float* __restrict__ Y)
{
    const int row = blockIdx.x;
    const int b = row >> 11;
    const int c = cid[row];
    const float* xp = XP + ((size_t)b * LSEQ + c) * 768;
    const float* h = H + (size_t)row * 768;
    float* y = Y + (size_t)row * 768;
    for (int d = threadIdx.x; d < 768; d += 256) y[d] = xp[d] + h[d];
}

// ===========================================================================
extern "C" void kernel_launch(void* const* d_in, const int* in_sizes, int n_in,
                              void* d_out, int out_size, void* d_ws, size_t ws_size,
                              hipStream_t stream)
{
    auto F = [&](int i) { return (const float*)d_in[i]; };

    struct SW { const float *wq, *wk, *wv, *wo, *w1, *w3, *w2, *ln1, *ln2, *nrm; };
    SW comp, proc, dec;
    const float *rw1, *rb1, *rw2, *rb2, *upw, *dnw;

    const bool sig = (in_sizes[11] == 589824);
    if (!sig) {
        comp = { F(1), F(2), F(3), F(4), F(5), F(6), F(7), F(8), F(9), F(10) };
        proc = { F(11), F(12), F(13), F(14), F(15), F(16), F(17), F(18), F(19), F(20) };
        dec  = { F(21), F(22), F(23), F(24), F(25), F(26), F(27), F(28), F(29), F(30) };
        rw1 = F(31); rb1 = F(32); rw2 = F(33); rb2 = F(34); upw = F(35); dnw = F(36);
    } else {
        comp = { F(1), F(2), F(3), F(4), F(5), F(7), F(6), F(8), F(9), F(10) };
        rw1 = F(11); rb1 = F(12); rw2 = F(13); rb2 = F(14); upw = F(15); dnw = F(16);
        proc = { F(17), F(18), F(19), F(20), F(21), F(23), F(22), F(24), F(25), F(26) };
        dec  = { F(27), F(28), F(29), F(30), F(31), F(33), F(32), F(34), F(35), F(36) };
    }

    // ---- workspace carve (aliased for footprint; liveness-verified) ----
    char* ws = (char*)d_ws;
    size_t off = 0;
    auto alloc = [&](size_t bytes) -> void* {
        void* p = ws + off;
        off = (off + bytes + 255) & ~(size_t)255;
        return p;
    };
    float* X    = (float*)alloc(4096ull * 1152 * 4);
    float* BigF = (float*)alloc(4096ull * 6144 * 4);   // QKV | T13(router) | XP (disjoint lifetimes)
    float* HC   = (float*)alloc(4096ull * 768 * 4);
    u16* HNhi   = (u16*)alloc(4096ull * 1152 * 2);     // also HC-split + gather G
    u16* HNlo   = (u16*)alloc(4096ull * 1152 * 2);
    u16* SWhi   = (u16*)alloc(4096ull * 3072 * 2);     // also attention O (disjoint)
    u16* SWlo   = (u16*)alloc(4096ull * 3072 * 2);
    u16* Khi    = (u16*)alloc(24ull * 2048 * 96 * 2);
    u16* Klo    = (u16*)alloc(24ull * 2048 * 96 * 2);
    u16* Vthi   = (u16*)alloc(24ull * 2048 * 96 * 2);
    u16* Vtlo   = (u16*)alloc(24ull * 2048 * 96 * 2);
    float* Pacc = (float*)alloc(24ull * 72 * 64 * 96 * 4);   // k-chunk partials (72 slots/bh)
    float* Pml  = (float*)alloc(24ull * 72 * 64 * 2 * 4);
    u16* qkvPhi = (u16*)alloc(3981312ull * 2);
    u16* qkvPlo = (u16*)alloc(3981312ull * 2);
    u16* woPhi  = (u16*)alloc(1327104ull * 2);
    u16* woPlo  = (u16*)alloc(1327104ull * 2);
    u16* w13Phi = (u16*)alloc(7077888ull * 2);
    u16* w13Plo = (u16*)alloc(7077888ull * 2);
    u16* w2Phi  = (u16*)alloc(3538944ull * 2);
    u16* w2Plo  = (u16*)alloc(3538944ull * 2);
    u16* rw1Phi = (u16*)alloc(589824ull * 2);
    u16* rw1Plo = (u16*)alloc(589824ull * 2);
    u16* upwPhi = (u16*)alloc(884736ull * 2);
    u16* upwPlo = (u16*)alloc(884736ull * 2);
    u16* dnwPhi = (u16*)alloc(884736ull * 2);
    u16* dnwPlo = (u16*)alloc(884736ull * 2);
    int* mask   = (int*)alloc(4096 * 4);
    int* cid    = (int*)alloc(4096 * 4);
    int* bnd    = (int*)alloc(4096 * 4);
    int* cnts   = (int*)alloc(2 * 4);
    int* dS     = (int*)alloc(256);
    float* c1   = (float*)alloc(2048ull * 32 * 4);
    float* s1   = (float*)alloc(2048ull * 32 * 4);
    float* c2   = (float*)alloc(2048ull * 48 * 4);
    float* s2   = (float*)alloc(2048ull * 48 * 4);

    float* QKV = BigF;              // lives: qkv-gemm .. fattn2
    float* T13 = BigF;              // lives: router gemm only
    float* XP  = BigF;              // lives: down-gemm .. ybuild
    u16* Ohi = SWhi;                // lives: fattn2 .. wo-gemm
    u16* Olo = SWlo;

    hipMemcpyAsync(X, F(0), 4096ull * 768 * 4, hipMemcpyDeviceToDevice, stream);
    ropetab_k<<<640, 256, 0, stream>>>(c1, s1, c2, s2);

    // ---- split router/up/down once ----
    {
        SplitArgs sa{};
        sa.ne = 3;
        sa.e[0] = { rw1, nullptr, nullptr, rw1Phi, rw1Plo, 768, 768, 1, 0, 0 };
        sa.e[1] = { upw, nullptr, nullptr, upwPhi, upwPlo, 768, 1152, 1, 288, 0 };
        sa.e[2] = { dnw, nullptr, nullptr, dnwPhi, dnwPlo, 1152, 768, 1, 720, 0 };
        wsplit_k<<<1152, 256, 0, stream>>>(sa);
    }

    // BM=64 everywhere (R10): 48KB LDS -> 3 blocks/CU, 2x block count.
    auto gemm = [&](const u16* ahi, const u16* alo, const u16* bhi, const u16* blo,
                    const float* res, float* c, int N, int K, const int* ds) {
        if (ds) gemm_mfma_k<true, false, 64><<<dim3(N / 128, 64), 256, 0, stream>>>(
                    ahi, alo, bhi, blo, res, c, nullptr, nullptr, N, K, ds);
        else    gemm_mfma_k<false, false, 64><<<dim3(N / 128, 64), 256, 0, stream>>>(
                    ahi, alo, bhi, blo, res, c, nullptr, nullptr, N, K, nullptr);
    };
    auto gemmswi = [&](const u16* ahi, const u16* alo, const u16* bhi, const u16* blo,
                       u16* shi, u16* slo, int N, int K, const int* ds) {
        if (ds) gemm_mfma_k<true, true, 64><<<dim3(N / 128, 64), 256, 0, stream>>>(
                    ahi, alo, bhi, blo, nullptr, nullptr, shi, slo, N, K, ds);
        else    gemm_mfma_k<false, true, 64><<<dim3(N / 128, 64), 256, 0, stream>>>(
                    ahi, alo, bhi, blo, nullptr, nullptr, shi, slo, N, K, nullptr);
    };

    auto run_layer = [&](const SW& W, int li, int dm, int ff, int hd,
                         const float* ct, const float* st, const int* ds) {
        const size_t wsz = (size_t)dm * dm;
        const float* wq = W.wq + (size_t)li * wsz;
        const float* wk = W.wk + (size_t)li * wsz;
        const float* wv = W.wv + (size_t)li * wsz;
        const float* wo = W.wo + (size_t)li * wsz;
        const float* w1 = W.w1 + (size_t)li * dm * ff;
        const float* w3 = W.w3 + (size_t)li * dm * ff;
        const float* w2 = W.w2 + (size_t)li * ff * dm;
        const float* ln1 = W.ln1 + (size_t)li * dm;
        const float* ln2 = W.ln2 + (size_t)li * dm;
        const float scale = 1.0f / sqrtf((float)hd);

        // pack this layer's weights (w1/w3 column-interleaved for fused swiglu)
        {
            const int b0 = dm * 3 * dm / 2048, b1 = dm * dm / 2048, b2 = dm * 2 * ff / 2048,
                      b3 = ff * dm / 2048;
            SplitArgs sa{};
            sa.ne = 4;
            sa.e[0] = { wq, wk, wv, qkvPhi, qkvPlo, dm, dm, 3, 0, 0 };
            sa.e[1] = { wo, nullptr, nullptr, woPhi, woPlo, dm, dm, 1, b0, 0 };
            sa.e[2] = { w1, w3, nullptr, w13Phi, w13Plo, dm, ff, 2, b0 + b1, 1 };
            sa.e[3] = { w2, nullptr, nullptr, w2Phi, w2Plo, ff, dm, 1, b0 + b1 + b2, 0 };
            wsplit_k<<<b0 + b1 + b2 + b3, 256, 0, stream>>>(sa);
        }

        rmsnorm_k<false, true><<<4096, 256, 0, stream>>>(X, ln1, nullptr, HNhi, HNlo, dm, ds);
        gemm(HNhi, HNlo, qkvPhi, qkvPlo, nullptr, QKV, 3 * dm, dm, ds);
        if (hd == 64) {
            prep_k<64><<<768, 256, 0, stream>>>(QKV, Khi, Klo, Vthi, Vtlo, ct, st, dm, ds);
            fattn2_k<64><<<1920, 256, 0, stream>>>(QKV, Khi, Klo, Vthi, Vtlo, Ohi, Olo, Pacc, Pml, dm, scale, ds);
            attn_merge_k<64><<<576, 256, 0, stream>>>(Pacc, Pml, Ohi, Olo, dm, ds);
        } else {
            prep_k<96><<<768, 256, 0, stream>>>(QKV, Khi, Klo, Vthi, Vtlo, ct, st, dm, ds);
            fattn2_k<96><<<1920, 256, 0, stream>>>(QKV, Khi, Klo, Vthi, Vtlo, Ohi, Olo, Pacc, Pml, dm, scale, ds);
            attn_merge_k<96><<<576, 256, 0, stream>>>(Pacc, Pml, Ohi, Olo, dm, ds);
        }
        gemm(Ohi, Olo, woPhi, woPlo, X, X, dm, dm, ds);
        rmsnorm_k<false, true><<<4096, 256, 0, stream>>>(X, ln2, nullptr, HNhi, HNlo, dm, ds);
        gemmswi(HNhi, HNlo, w13Phi, w13Plo, SWhi, SWlo, 2 * ff, dm, ds);
        gemm(SWhi, SWlo, w2Phi, w2Plo, X, X, dm, ff, ds);
    };

    // ---- compressor trunk (dense) ----
    for (int i = 0; i < 3; ++i) run_layer(comp, i, 768, 2048, 64, c1, s1, nullptr);
    rmsnorm_k<true, true><<<4096, 256, 0, stream>>>(X, comp.nrm, HC, HNhi, HNlo, 768, nullptr);

    // ---- router (HNhi/HNlo hold split HC here) ----
    gemm(HNhi, HNlo, rw1Phi, rw1Plo, nullptr, T13, 768, 768, nullptr);
    router2_k<<<4096, 256, 0, stream>>>(T13, rb1, rw2, rb2, mask);
    scan_k<<<2, 256, 0, stream>>>(mask, cid, bnd, cnts);
    smax_k<<<1, 64, 0, stream>>>(cnts, dS);

    // ---- gather (reuses HNhi/HNlo as G) + up-projection ----
    gather_k<<<dim3(LSEQ, 2), 256, 0, stream>>>(HC, bnd, cnts, HNhi, HNlo);
    gemm(HNhi, HNlo, upwPhi, upwPlo, nullptr, X, 1152, 768, dS);

    // ---- processor stack (padded) ----
    for (int i = 0; i < 6; ++i) run_layer(proc, i, 1152, 3072, 96, c2, s2, dS);
    rmsnorm_k<false, true><<<4096, 256, 0, stream>>>(X, proc.nrm, nullptr, HNhi, HNlo, 1152, dS);
    gemm(HNhi, HNlo, dnwPhi, dnwPlo, nullptr, XP, 768, 1152, dS);

    // ---- scatter back + decoder (dense) ----
    ybuild_k<<<4096, 256, 0, stream>>>(XP, HC, cid, X);
    for (int i = 0; i < 3; ++i) run_layer(dec, i, 768, 2048, 64, c1, s1, nullptr);
    rmsnorm_k<true, false><<<4096, 256, 0, stream>>>(X, dec.nrm, (float*)d_out, nullptr, nullptr, 768, nullptr);
}

// Round 12
// 4245.978 us; speedup vs baseline: 1.0226x; 1.0010x over previous
//
#include <hip/hip_runtime.h>
#include <cstdint>

static constexpr int LSEQ = 2048;
static constexpr int NHEAD = 12;

typedef unsigned short u16;
typedef __attribute__((ext_vector_type(8))) short bf16x8;
typedef __attribute__((ext_vector_type(8))) unsigned short u16x8;
typedef __attribute__((ext_vector_type(4))) unsigned short u16x4;
typedef __attribute__((ext_vector_type(4))) float f32x4;

#define MFMA16 __builtin_amdgcn_mfma_f32_16x16x32_bf16

union U8cvt { u16 u[8]; bf16x8 v; u16x8 w; };

__device__ __forceinline__ float silu(float a) { return a / (1.f + __expf(-a)); }

// round-to-nearest-even fp32 -> bf16 hi/lo split
__device__ __forceinline__ void splitf(float x, u16& h, u16& l) {
    uint32_t ux = __float_as_uint(x);
    uint32_t uh = (ux + 0x7fffu + ((ux >> 16) & 1u)) >> 16;
    float hf = __uint_as_float(uh << 16);
    float r = x - hf;
    uint32_t ur = __float_as_uint(r);
    uint32_t ul = (ur + 0x7fffu + ((ur >> 16) & 1u)) >> 16;
    h = (u16)uh; l = (u16)ul;
}

__device__ __forceinline__ void gld16(const void* g, void* l) {
    __builtin_amdgcn_global_load_lds((const __attribute__((address_space(1))) void*)g,
                                     (__attribute__((address_space(3))) void*)l, 16, 0, 0);
}

// bh->XCD affinity decode: wgid = (bh%8) + 8*((bh/8)*NXB + x).
// All blocks of one bh land on xcd = bh%8 (assuming xcd = wgid%8 round-robin)
// -> that XCD's L2 retains the bh's K/V panel across its 80 blocks.
// [R7 verified on attn: FETCH 103->18.5MB. R8 showed this class of swizzle
//  HURTS the GEMMs (B re-streamed per XCD) -> GEMMs keep plain 2D grids.]
__device__ __forceinline__ void bh_decode(int wg, int NXB, int& x, int& bh) {
    const int c8 = wg & 7;
    const int r = wg >> 3;
    x = r % NXB;
    bh = (r / NXB) * 8 + c8;
}

// ---------------- weight pre-split: fp32 [K][Nper] x nsrc -> packed bf16 ---
// ilv=1 (nsrc=2): packed col 2j = s0 col j, 2j+1 = s1 col j (for fused swiglu)
struct SplitEnt { const float* s0; const float* s1; const float* s2;
                  u16* dhi; u16* dlo; int K; int Nper; int nsrc; int bstart; int ilv; };
struct SplitArgs { SplitEnt e[4]; int ne; };

__global__ __launch_bounds__(256)
void wsplit_k(SplitArgs a)
{
    const int blk = blockIdx.x;
    int ti = a.ne - 1;
    for (int i = 1; i < a.ne; ++i) if (blk < a.e[i].bstart) { ti = i - 1; break; }
    const SplitEnt E = a.e[ti];
    const int N = E.Nper * E.nsrc;
    const int u = (blk - E.bstart) * 256 + threadIdx.x;
    const int n = u % N, kb = u / N;
    int which, col;
    if (E.ilv) { which = n & 1; col = n >> 1; }
    else       { which = n / E.Nper; col = n - which * E.Nper; }
    const float* sp = (which == 0 ? E.s0 : which == 1 ? E.s1 : E.s2)
                      + (size_t)(kb * 8) * E.Nper + col;
    U8cvt hh, ll;
#pragma unroll
    for (int j = 0; j < 8; ++j) splitf(sp[(size_t)j * E.Nper], hh.u[j], ll.u[j]);
    *(u16x8*)(E.dhi + (size_t)u * 8) = hh.w;
    *(u16x8*)(E.dlo + (size_t)u * 8) = ll.w;
}

// ================= MFMA split-precision GEMM, packed-weight B ==============
// BM=64 everywhere (R10): 48KB LDS -> 3 blocks/CU residency, 2x block count.
// Plain 2D grid (n fastest): concurrent blocks share the A-row band via L3
// and each block's B col-panel L2-fits. [R8: chunked XCD swizzle here HURT.]
// SWI: fused SwiGLU epilogue (B is w1/w3 column-interleaved; writes split
// bf16 silu(a)*g to Shi/Slo with row stride N/2).
template<bool MASK, bool SWI, int BM>
__global__ __launch_bounds__(256)
void gemm_mfma_k(const u16* __restrict__ Ahi, const u16* __restrict__ Alo,
                 const u16* __restrict__ Bhi, const u16* __restrict__ Blo,
                 const float* __restrict__ Res, float* __restrict__ C,
                 u16* __restrict__ Shi, u16* __restrict__ Slo,
                 int N, int K, const int* __restrict__ dS)
{
    constexpr int MFR = BM / 32;             // m-fragments per wave (4 or 2)
    constexpr int AI  = BM / 32;             // A-staging iters (4 or 2)
    const int n0 = blockIdx.x * 128;
    const int m0 = blockIdx.y * BM;
    int S = 1 << 30;
    if (MASK) { S = *dS; if ((m0 & (LSEQ - 1)) >= S) return; }

    __shared__ u16 sm[2 * BM * 64 + 16384];  // A(hi,lo) + B(hi,lo)
    u16* sAhi = sm;
    u16* sAlo = sm + BM * 64;
    u16* sBhi = sm + 2 * BM * 64;
    u16* sBlo = sBhi + 8192;

    const int t = threadIdx.x;
    const int w = t >> 6, lane = t & 63;
    const int wm = (w >> 1) * (BM / 2), wn = (w & 1) * 64;
    const int l15 = lane & 15, l4 = lane >> 4, l7 = lane & 7;

    const f32x4 zf = {0.f, 0.f, 0.f, 0.f};
    f32x4 acc[MFR][4];
#pragma unroll
    for (int i = 0; i < MFR; ++i)
#pragma unroll
        for (int j = 0; j < 4; ++j) acc[i][j] = zf;

    for (int k0 = 0; k0 < K; k0 += 64) {
        __syncthreads();
        // A: pre-swizzled source, linear LDS
#pragma unroll
        for (int i = 0; i < AI; ++i) {
            const int q = i * 256 + t;
            const int mrow = q >> 3;
            const int u = (q & 7) ^ (mrow & 7);
            const size_t goff = (size_t)(m0 + mrow) * K + k0 + u * 8;
            const int lbase = i * 2048 + w * 512;
            gld16(Ahi + goff, (void*)(sAhi + lbase));
            gld16(Alo + goff, (void*)(sAlo + lbase));
        }
        // B: packed k-unit layout, direct linear stage
#pragma unroll
        for (int i = 0; i < 4; ++i) {
            const int q = i * 256 + t;
            const size_t goff = ((size_t)((k0 >> 3) + (q >> 7)) * N + n0 + (q & 127)) * 8;
            const int lbase = i * 2048 + w * 512;
            gld16(Bhi + goff, (void*)(sBhi + lbase));
            gld16(Blo + goff, (void*)(sBlo + lbase));
        }
        __syncthreads();

#pragma unroll
        for (int kk = 0; kk < 2; ++kk) {
            bf16x8 ah[MFR], al[MFR], bh[4], bl[4];
#pragma unroll
            for (int mf = 0; mf < MFR; ++mf) {
                const int row = wm + mf * 16 + l15;
                const int idx = row * 64 + (((kk * 4 + l4) ^ l7) * 8);
                ah[mf] = *(const bf16x8*)(sAhi + idx);
                al[mf] = *(const bf16x8*)(sAlo + idx);
            }
#pragma unroll
            for (int nf = 0; nf < 4; ++nf) {
                const int idx = ((kk * 4 + l4) * 128 + wn + nf * 16 + l15) * 8;
                bh[nf] = *(const bf16x8*)(sBhi + idx);
                bl[nf] = *(const bf16x8*)(sBlo + idx);
            }
#pragma unroll
            for (int mf = 0; mf < MFR; ++mf)
#pragma unroll
                for (int nf = 0; nf < 4; ++nf) {
                    acc[mf][nf] = MFMA16(ah[mf], bh[nf], acc[mf][nf], 0, 0, 0);
                    acc[mf][nf] = MFMA16(ah[mf], bl[nf], acc[mf][nf], 0, 0, 0);
                    acc[mf][nf] = MFMA16(al[mf], bh[nf], acc[mf][nf], 0, 0, 0);
                }
        }
    }

#pragma unroll
    for (int mf = 0; mf < MFR; ++mf) {
#pragma unroll
        for (int r = 0; r < 4; ++r) {
            const int gr = m0 + wm + mf * 16 + l4 * 4 + r;
            if (MASK && (gr & (LSEQ - 1)) >= S) continue;   // pair-uniform (l4,r)
#pragma unroll
            for (int nf = 0; nf < 4; ++nf) {
                const int gc = n0 + wn + nf * 16 + l15;
                float v = acc[mf][nf][r];
                if (SWI) {
                    const float o = __shfl_xor(v, 1);       // partner column
                    if (!(l15 & 1)) {                       // even col = a (w1)
                        const float rr = silu(v) * o;
                        u16 hh, ll; splitf(rr, hh, ll);
                        const size_t bo = (size_t)gr * (N >> 1) + (gc >> 1);
                        Shi[bo] = hh; Slo[bo] = ll;
                    }
                } else {
                    float vv = v;
                    if (Res) vv += Res[(size_t)gr * N + gc];
                    C[(size_t)gr * N + gc] = vv;
                }
            }
        }
    }
}

// ---------------- RMSNorm (float4-vectorized loads/stores, G13) ------------
template<bool F32OUT, bool SPLITOUT>
__global__ __launch_bounds__(256)
void rmsnorm_k(const float* __restrict__ X, const float* __restrict__ w,
               float* __restrict__ OutF, u16* __restrict__ Ohi, u16* __restrict__ Olo,
               int D, const int* __restrict__ dS)
{
    const int row = blockIdx.x;
    if (dS && (row & (LSEQ - 1)) >= *dS) return;
    const float* xr = X + (size_t)row * D;
    const int D4 = D >> 2;
    float ss = 0.f;
    for (int d4 = threadIdx.x; d4 < D4; d4 += 256) {
        const float4 v = *(const float4*)(xr + d4 * 4);
        ss += v.x * v.x + v.y * v.y + v.z * v.z + v.w * v.w;
    }
#pragma unroll
    for (int off = 1; off < 64; off <<= 1) ss += __shfl_xor(ss, off);
    __shared__ float red[4];
    if ((threadIdx.x & 63) == 0) red[threadIdx.x >> 6] = ss;
    __syncthreads();
    const float tot = red[0] + red[1] + red[2] + red[3];
    const float rs = rsqrtf(tot / (float)D + 1e-5f);
    for (int d4 = threadIdx.x; d4 < D4; d4 += 256) {
        const float4 v = *(const float4*)(xr + d4 * 4);
        const float4 wv = *(const float4*)(w + d4 * 4);
        float y[4] = { v.x * rs * wv.x, v.y * rs * wv.y,
                       v.z * rs * wv.z, v.w * rs * wv.w };
        if (F32OUT) {
            float4 o = { y[0], y[1], y[2], y[3] };
            *(float4*)(OutF + (size_t)row * D + d4 * 4) = o;
        }
        if (SPLITOUT) {
            u16x4 hv, lv;
#pragma unroll
            for (int j = 0; j < 4; ++j) { u16 h, l; splitf(y[j], h, l); hv[j] = h; lv[j] = l; }
            *(u16x4*)(Ohi + (size_t)row * D + d4 * 4) = hv;
            *(u16x4*)(Olo + (size_t)row * D + d4 * 4) = lv;
        }
    }
}

// ---------------- RoPE tables ----------------------------------------------
__global__ void ropetab_k(float* c1, float* s1, float* c2, float* s2)
{
    const int idx = blockIdx.x * 256 + threadIdx.x;
    if (idx < 2048 * 32) {
        const int pos = idx >> 5, i = idx & 31;
        const float th = powf(10000.f, -(float)(2 * i) / 64.f);
        const float v = (float)pos * th;
        c1[idx] = cosf(v); s1[idx] = sinf(v);
    }
    const int idx2 = idx - 2048 * 32;
    if (idx2 >= 0 && idx2 < 2048 * 48) {
        const int pos = idx2 / 48, i = idx2 - (idx2 / 48) * 48;
        const float th = powf(10000.f, -(float)(2 * i) / 96.f);
        const float v = (float)pos * th;
        c2[idx2] = cosf(v); s2[idx2] = sinf(v);
    }
}

// ---------------- prep: Q rope in place, K rope->split, V->transposed split
// 1D grid with bh->XCD affinity (NXB=32): K/V writes land in xcd=bh%8's L2.
// R11: float4-vectorized rope (4 i-positions/iter) + u16x4 K/LDS stores.
template<int HD>
__global__ __launch_bounds__(256)
void prep_k(float* __restrict__ QKV, u16* __restrict__ Khi, u16* __restrict__ Klo,
            u16* __restrict__ Vthi, u16* __restrict__ Vtlo,
            const float* __restrict__ ct, const float* __restrict__ st,
            int dm, const int* __restrict__ dS)
{
    constexpr int half = HD / 2;
    constexpr int H4 = half / 4;           // 8 @HD64, 12 @HD96
    int xb, bh;
    bh_decode(blockIdx.x, 32, xb, bh);
    const int s0 = xb * 64;
    if (dS && s0 >= *dS) return;
    const int b = bh / NHEAD, h = bh - b * NHEAD;
    const int qstride = 3 * dm;
    const int t = threadIdx.x;

    // ---- Q/K rope (vectorized over 4 consecutive i) ----
    for (int e = t; e < 64 * H4; e += 256) {
        const int row = e / H4, i4 = e - row * H4;
        const int i = i4 * 4;
        const int pos = s0 + row;
        const float4 c  = *(const float4*)(ct + pos * half + i);
        const float4 sn = *(const float4*)(st + pos * half + i);
        const size_t g = (size_t)(b * LSEQ + pos) * qstride + h * HD + i;
        // Q in place
        float4 x1 = *(const float4*)(QKV + g);
        float4 x2 = *(const float4*)(QKV + g + half);
        float4 o1, o2;
        o1.x = x1.x * c.x - x2.x * sn.x;  o2.x = x2.x * c.x + x1.x * sn.x;
        o1.y = x1.y * c.y - x2.y * sn.y;  o2.y = x2.y * c.y + x1.y * sn.y;
        o1.z = x1.z * c.z - x2.z * sn.z;  o2.z = x2.z * c.z + x1.z * sn.z;
        o1.w = x1.w * c.w - x2.w * sn.w;  o2.w = x2.w * c.w + x1.w * sn.w;
        *(float4*)(QKV + g) = o1;
        *(float4*)(QKV + g + half) = o2;
        // K -> split
        const size_t gk = g + dm;
        float4 y1 = *(const float4*)(QKV + gk);
        float4 y2 = *(const float4*)(QKV + gk + half);
        float k1[4] = { y1.x * c.x - y2.x * sn.x, y1.y * c.y - y2.y * sn.y,
                        y1.z * c.z - y2.z * sn.z, y1.w * c.w - y2.w * sn.w };
        float k2[4] = { y2.x * c.x + y1.x * sn.x, y2.y * c.y + y1.y * sn.y,
                        y2.z * c.z + y1.z * sn.z, y2.w * c.w + y1.w * sn.w };
        u16x4 h1, l1, h2, l2;
#pragma unroll
        for (int j = 0; j < 4; ++j) {
            u16 hh, ll;
            splitf(k1[j], hh, ll); h1[j] = hh; l1[j] = ll;
            splitf(k2[j], hh, ll); h2[j] = hh; l2[j] = ll;
        }
        const size_t ko = ((size_t)bh * LSEQ + pos) * HD + i;
        *(u16x4*)(Khi + ko) = h1;        *(u16x4*)(Klo + ko) = l1;
        *(u16x4*)(Khi + ko + half) = h2; *(u16x4*)(Klo + ko + half) = l2;
    }

    // ---- V transpose split ----
    __shared__ u16 sh[64][HD], sl[64][HD];
    constexpr int C4 = HD / 4;
#pragma unroll
    for (int it = 0; it < 64 * C4 / 256; ++it) {
        const int q = it * 256 + t;
        const int row = q / C4, c4 = q - row * C4;
        const float4 v = *(const float4*)(QKV + (size_t)(b * LSEQ + s0 + row) * qstride
                                          + 2 * dm + h * HD + c4 * 4);
        u16x4 hv, lv;
        { u16 hh, ll; splitf(v.x, hh, ll); hv[0] = hh; lv[0] = ll; }
        { u16 hh, ll; splitf(v.y, hh, ll); hv[1] = hh; lv[1] = ll; }
        { u16 hh, ll; splitf(v.z, hh, ll); hv[2] = hh; lv[2] = ll; }
        { u16 hh, ll; splitf(v.w, hh, ll); hv[3] = hh; lv[3] = ll; }
        *(u16x4*)&sh[row][c4 * 4] = hv;
        *(u16x4*)&sl[row][c4 * 4] = lv;
    }
    __syncthreads();
    const int s8 = t & 7, d0 = t >> 3;
    for (int d = d0; d < HD; d += 32) {
        U8cvt hh, ll;
#pragma unroll
        for (int j = 0; j < 8; ++j) { hh.u[j] = sh[s8 * 8 + j][d]; ll.u[j] = sl[s8 * 8 + j][d]; }
        const size_t vo = ((size_t)bh * HD + d) * LSEQ + s0 + s8 * 8;
        *(u16x8*)(Vthi + vo) = hh.w;
        *(u16x8*)(Vtlo + vo) = ll.w;
    }
}

// ================= MFMA flash attention v8: uniform k-chunks + XCD affinity
// Causal load-balance: q-tile j (64 rows) is processed by nc(j) blocks, each
// covering a contiguous k-chunk of <=8 tiles:
//   j 0..7: nc=1 (direct O write), 8..15: nc=2, 16..23: nc=3, 24..31: nc=4.
// 80 x-blocks per bh; 1D grid 1920 with bh->XCD affinity: all 80 blocks of a
// bh run on xcd=bh%8 -> its 1MB (HD64) K/V panel stays L2-resident (3 bh x
// 1MB per 4MB L2). [R7 measured: FETCH 103->18.5MB, dur 97->91us]
template<int HD>
__device__ __forceinline__ int kswz(int u, int r) {
    if constexpr (HD == 64) return u ^ (r & 7);
    else return (u & 12) | ((u & 3) ^ (r & 3));
}

__device__ __forceinline__ int slot_of(int j, int c) {
    if (j < 16) return 2 * (j - 8) + c;          // j 8..15
    if (j < 24) return 16 + 3 * (j - 16) + c;    // j 16..23
    return 40 + 4 * (j - 24) + c;                // j 24..31
}

template<int HD>
__global__ __launch_bounds__(256)
void fattn2_k(const float* __restrict__ QKV, const u16* __restrict__ Khi,
              const u16* __restrict__ Klo, const u16* __restrict__ Vthi,
              const u16* __restrict__ Vtlo, u16* __restrict__ Ohi,
              u16* __restrict__ Olo, float* __restrict__ Pacc,
              float* __restrict__ Pml, int dm, float scale,
              const int* __restrict__ dS)
{
    constexpr int BK = 64;
    constexpr int KG8 = HD / 8;
    constexpr int KO = HD / 32;
    constexpr int NFP = HD / 16;
    constexpr float NEG = -3.0e38f;

    int x, bh;
    bh_decode(blockIdx.x, 80, x, bh);            // x 0..79, bh 0..23
    int j, c, nc;
    if (x < 8)       { j = x;                c = 0;            nc = 1; }
    else if (x < 24) { j = 8 + ((x - 8) >> 1);  c = (x - 8) & 1;  nc = 2; }
    else if (x < 48) { j = 16 + (x - 24) / 3;   c = (x - 24) % 3; nc = 3; }
    else             { j = 24 + ((x - 48) >> 2); c = (x - 48) & 3; nc = 4; }
    const int q0 = j * 64;
    int S = 1 << 30;
    if (dS) { S = *dS; if (q0 >= S) return; }
    const int T = j + 1;                         // causal k-tiles for this j
    const int cb = T / nc, crem = T - cb * nc;
    const int cnt = cb + (c < crem ? 1 : 0);
    const int st  = c * cb + (c < crem ? c : crem);
    const int kbeg = st * BK;
    const int kend = (st + cnt) * BK;

    const int b = bh / NHEAD, h = bh - b * NHEAD;
    const int qstride = 3 * dm;

    __shared__ u16 smem[2 * BK * HD + 2 * HD * BK + 4 * 2 * 16 * 64];
    u16* sKhi = smem;
    u16* sKlo = sKhi + BK * HD;
    u16* sVhi = sKlo + BK * HD;
    u16* sVlo = sVhi + HD * BK;
    u16* sP   = sVlo + HD * BK;

    const int t = threadIdx.x;
    const int w = t >> 6, lane = t & 63;
    const int l15 = lane & 15, l4 = lane >> 4;
    u16* sPhi = sP + w * (2 * 16 * 64);
    u16* sPlo = sPhi + 16 * 64;

    const int qbase = q0 + w * 16;

    // ---- Q fragments (scaled + split, registers) ----
    bf16x8 qh[KO], ql[KO];
    {
        const float* qp = QKV + (size_t)(b * LSEQ + qbase + l15) * qstride + h * HD;
#pragma unroll
        for (int ki = 0; ki < KO; ++ki) {
            const float* p = qp + (ki * 4 + l4) * 8;
            U8cvt hh, ll;
#pragma unroll
            for (int jj = 0; jj < 8; ++jj) splitf(p[jj] * scale, hh.u[jj], ll.u[jj]);
            qh[ki] = hh.v; ql[ki] = ll.v;
        }
    }

    float m[4], l[4];
#pragma unroll
    for (int r = 0; r < 4; ++r) { m[r] = NEG; l[r] = 0.f; }
    const f32x4 zf = {0.f, 0.f, 0.f, 0.f};
    f32x4 acc[NFP];
#pragma unroll
    for (int nf = 0; nf < NFP; ++nf) acc[nf] = zf;

    const size_t kbase = (size_t)bh * LSEQ * HD;
    const size_t vbase = (size_t)bh * HD * LSEQ;

    for (int k0 = kbeg; k0 < kend; k0 += BK) {
        __syncthreads();
        // ---- stage K tile (pre-swizzled source, linear LDS) ----
#pragma unroll
        for (int it = 0; it < BK * KG8 / 256; ++it) {
            const int q = it * 256 + t;
            const int r = q / KG8, u = q - r * KG8;
            const int us = kswz<HD>(u, r);
            const size_t go = kbase + (size_t)(k0 + r) * HD + us * 8;
            gld16(Khi + go, (void*)(sKhi + it * 2048 + w * 512));
            gld16(Klo + go, (void*)(sKlo + it * 2048 + w * 512));
        }
        // ---- stage Vt tile ----
#pragma unroll
        for (int it = 0; it < HD * 8 / 256; ++it) {
            const int q = it * 256 + t;
            const int d = q >> 3, u = q & 7;
            const int us = u ^ (d & 7);
            const size_t go = vbase + (size_t)d * LSEQ + k0 + us * 8;
            gld16(Vthi + go, (void*)(sVhi + it * 2048 + w * 512));
            gld16(Vtlo + go, (void*)(sVlo + it * 2048 + w * 512));
        }
        __syncthreads();

        // ---- scores ----
        f32x4 sc[4];
#pragma unroll
        for (int kf = 0; kf < 4; ++kf) sc[kf] = zf;
        __builtin_amdgcn_s_setprio(1);
#pragma unroll
        for (int kf = 0; kf < 4; ++kf) {
            const int row = kf * 16 + l15;
#pragma unroll
            for (int ki = 0; ki < KO; ++ki) {
                const int idx = row * HD + kswz<HD>(ki * 4 + l4, row) * 8;
                const bf16x8 kh = *(const bf16x8*)(sKhi + idx);
                const bf16x8 kl = *(const bf16x8*)(sKlo + idx);
                sc[kf] = MFMA16(qh[ki], kh, sc[kf], 0, 0, 0);
                sc[kf] = MFMA16(qh[ki], kl, sc[kf], 0, 0, 0);
                sc[kf] = MFMA16(ql[ki], kh, sc[kf], 0, 0, 0);
            }
        }
        __builtin_amdgcn_s_setprio(0);

        if (k0 + 63 > qbase) {             // near-diagonal: causal mask
            const int qg = qbase + l4 * 4;
#pragma unroll
            for (int kf = 0; kf < 4; ++kf) {
                const int jc = k0 + kf * 16 + l15;
#pragma unroll
                for (int r = 0; r < 4; ++r)
                    if (jc > qg + r) sc[kf][r] = NEG;
            }
        }

        // ---- online softmax + swizzled P write + rescale ----
        {
            float fac[4];
#pragma unroll
            for (int r = 0; r < 4; ++r) {
                float mx = fmaxf(fmaxf(sc[0][r], sc[1][r]),
                                 fmaxf(sc[2][r], sc[3][r]));
                mx = fmaxf(mx, __shfl_xor(mx, 1));
                mx = fmaxf(mx, __shfl_xor(mx, 2));
                mx = fmaxf(mx, __shfl_xor(mx, 4));
                mx = fmaxf(mx, __shfl_xor(mx, 8));
                const float mn = fmaxf(m[r], mx);
                fac[r] = __expf(m[r] - mn);
                float rs = 0.f;
                float pv[4];
#pragma unroll
                for (int kf = 0; kf < 4; ++kf) { pv[kf] = __expf(sc[kf][r] - mn); rs += pv[kf]; }
                rs += __shfl_xor(rs, 1);
                rs += __shfl_xor(rs, 2);
                rs += __shfl_xor(rs, 4);
                rs += __shfl_xor(rs, 8);
                l[r] = l[r] * fac[r] + rs;
                m[r] = mn;
                const int prow = l4 * 4 + r;
                const int rx = prow & 7;
#pragma unroll
                for (int kf = 0; kf < 4; ++kf) {
                    u16 hh, ll; splitf(pv[kf], hh, ll);
                    const int a = prow * 64 + (((kf * 2 + (l15 >> 3)) ^ rx) * 8) + (l15 & 7);
                    sPhi[a] = hh; sPlo[a] = ll;
                }
            }
#pragma unroll
            for (int nf = 0; nf < NFP; ++nf)
#pragma unroll
                for (int r = 0; r < 4; ++r) acc[nf][r] *= fac[r];
        }

        // ---- PV ----
        bf16x8 ph[2], pl[2];
#pragma unroll
        for (int kk = 0; kk < 2; ++kk) {
            const int a = l15 * 64 + (((kk * 4 + l4) ^ (l15 & 7)) * 8);
            ph[kk] = *(const bf16x8*)(sPhi + a);
            pl[kk] = *(const bf16x8*)(sPlo + a);
        }
        __builtin_amdgcn_s_setprio(1);
#pragma unroll
        for (int nf = 0; nf < NFP; ++nf) {
            const int row = nf * 16 + l15;
#pragma unroll
            for (int kk = 0; kk < 2; ++kk) {
                const int idx = row * 64 + ((kk * 4 + l4) ^ (row & 7)) * 8;
                const bf16x8 vh = *(const bf16x8*)(sVhi + idx);
                const bf16x8 vl = *(const bf16x8*)(sVlo + idx);
                acc[nf] = MFMA16(ph[kk], vh, acc[nf], 0, 0, 0);
                acc[nf] = MFMA16(ph[kk], vl, acc[nf], 0, 0, 0);
                acc[nf] = MFMA16(pl[kk], vh, acc[nf], 0, 0, 0);
            }
        }
        __builtin_amdgcn_s_setprio(0);
    }

    // ---- epilogue ----
    if (nc == 1) {
#pragma unroll
        for (int r = 0; r < 4; ++r) {
            const float rl = 1.f / l[r];
            const size_t ro = (size_t)(b * LSEQ + qbase + l4 * 4 + r) * dm + h * HD;
#pragma unroll
            for (int nf = 0; nf < NFP; ++nf) {
                u16 hh, ll; splitf(acc[nf][r] * rl, hh, ll);
                Ohi[ro + nf * 16 + l15] = hh;
                Olo[ro + nf * 16 + l15] = ll;
            }
        }
    } else {
        const int pi = bh * 72 + slot_of(j, c);
#pragma unroll
        for (int r = 0; r < 4; ++r) {
            const int row = w * 16 + l4 * 4 + r;
            float* pa = Pacc + ((size_t)pi * 64 + row) * HD;
#pragma unroll
            for (int nf = 0; nf < NFP; ++nf)
                pa[nf * 16 + l15] = acc[nf][r];
            if (l15 == 0) {
                Pml[((size_t)pi * 64 + row) * 2 + 0] = m[r];
                Pml[((size_t)pi * 64 + row) * 2 + 1] = l[r];
            }
        }
    }
}

// ---------------- merge nc k-chunk partials -> O ---------------------------
// 1D grid (NXB=24) with same bh->XCD affinity: reads Pacc from the XCD's L2.
// R11: float4 Pacc reads + u16x4 O writes (same accumulation order).
template<int HD>
__global__ __launch_bounds__(256)
void attn_merge_k(const float* __restrict__ Pacc, const float* __restrict__ Pml,
                  u16* __restrict__ Ohi, u16* __restrict__ Olo,
                  int dm, const int* __restrict__ dS)
{
    int jx, bh;
    bh_decode(blockIdx.x, 24, jx, bh);
    const int j = 8 + jx;                      // 8..31
    const int q0 = j * 64;
    if (dS && q0 >= *dS) return;
    const int b = bh / NHEAD, h = bh - b * NHEAD;
    const int nc = (j < 16) ? 2 : (j < 24) ? 3 : 4;
    const int pbase = bh * 72 + slot_of(j, 0);

    __shared__ float wsm[4][64], invs[64];
    const int t = threadIdx.x;
    if (t < 64) {
        float m0, m1, m2 = -3.0e38f, m3 = -3.0e38f;
        float l0, l1, l2 = 0.f, l3 = 0.f;
        m0 = Pml[((size_t)(pbase + 0) * 64 + t) * 2];
        l0 = Pml[((size_t)(pbase + 0) * 64 + t) * 2 + 1];
        m1 = Pml[((size_t)(pbase + 1) * 64 + t) * 2];
        l1 = Pml[((size_t)(pbase + 1) * 64 + t) * 2 + 1];
        if (nc > 2) {
            m2 = Pml[((size_t)(pbase + 2) * 64 + t) * 2];
            l2 = Pml[((size_t)(pbase + 2) * 64 + t) * 2 + 1];
        }
        if (nc > 3) {
            m3 = Pml[((size_t)(pbase + 3) * 64 + t) * 2];
            l3 = Pml[((size_t)(pbase + 3) * 64 + t) * 2 + 1];
        }
        const float mm = fmaxf(fmaxf(m0, m1), fmaxf(m2, m3));
        const float w0 = __expf(m0 - mm);
        const float w1 = __expf(m1 - mm);
        const float w2 = (nc > 2) ? __expf(m2 - mm) : 0.f;
        const float w3 = (nc > 3) ? __expf(m3 - mm) : 0.f;
        wsm[0][t] = w0; wsm[1][t] = w1; wsm[2][t] = w2; wsm[3][t] = w3;
        invs[t] = 1.f / (w0 * l0 + w1 * l1 + w2 * l2 + w3 * l3);
    }
    __syncthreads();
    constexpr int HD4 = HD / 4;
    for (int e = t; e < 64 * HD4; e += 256) {
        const int row = e / HD4, d4 = e - row * HD4;
        const size_t pb = (size_t)pbase * 64;
        const float4 a0 = *(const float4*)(Pacc + (pb + 0 * 64 + row) * HD + d4 * 4);
        const float4 a1 = *(const float4*)(Pacc + (pb + 1 * 64 + row) * HD + d4 * 4);
        const float w0 = wsm[0][row], w1 = wsm[1][row];
        float o[4] = { w0 * a0.x + w1 * a1.x, w0 * a0.y + w1 * a1.y,
                       w0 * a0.z + w1 * a1.z, w0 * a0.w + w1 * a1.w };
        if (nc > 2) {
            const float4 a2 = *(const float4*)(Pacc + (pb + 2 * 64 + row) * HD + d4 * 4);
            const float w2 = wsm[2][row];
            o[0] += w2 * a2.x; o[1] += w2 * a2.y; o[2] += w2 * a2.z; o[3] += w2 * a2.w;
        }
        if (nc > 3) {
            const float4 a3 = *(const float4*)(Pacc + (pb + 3 * 64 + row) * HD + d4 * 4);
            const float w3 = wsm[3][row];
            o[0] += w3 * a3.x; o[1] += w3 * a3.y; o[2] += w3 * a3.z; o[3] += w3 * a3.w;
        }
        const float iv = invs[row];
        u16x4 hv, lv;
#pragma unroll
        for (int jj = 0; jj < 4; ++jj) { u16 hh, ll; splitf(o[jj] * iv, hh, ll); hv[jj] = hh; lv[jj] = ll; }
        const size_t ro = (size_t)(b * LSEQ + q0 + row) * dm + h * HD + d4 * 4;
        *(u16x4*)(Ohi + ro) = hv;
        *(u16x4*)(Olo + ro) = lv;
    }
}

// ---------------- Router stage 2 (kept scalar: logit sum order must not
// change -- a reordered reduction could flip a near-zero routing decision) --
__global__ __launch_bounds__(256)
void router2_k(const float* __restrict__ T, const float* __restrict__ b1,
               const float* __restrict__ w2, const float* __restrict__ b2,
               int* __restrict__ mask)
{
    const int row = blockIdx.x;
    const float* tr = T + (size_t)row * 768;
    float p = 0.f;
    for (int d = threadIdx.x; d < 768; d += 256) {
        const float u = tr[d] + b1[d];
        p += u / (1.f + __expf(-u)) * w2[d];
    }
#pragma unroll
    for (int off = 1; off < 64; off <<= 1) p += __shfl_xor(p, off);
    __shared__ float red[4];
    if ((threadIdx.x & 63) == 0) red[threadIdx.x >> 6] = p;
    __syncthreads();
    if (threadIdx.x == 0) {
        const float logit = red[0] + red[1] + red[2] + red[3] + b2[0];
        mask[row] = ((row & (LSEQ - 1)) == 0 || logit > 0.f) ? 1 : 0;
    }
}

// ---------------- Per-batch inclusive scan + boundaries --------------------
__global__ __launch_bounds__(256)
void scan_k(const int* __restrict__ mask, int* __restrict__ cid,
            int* __restrict__ bnd, int* __restrict__ counts)
{
    const int b = blockIdx.x, t = threadIdx.x;
    const int base = b * LSEQ;
    __shared__ int lds[256];
    int loc[8]; int s = 0;
#pragma unroll
    for (int j = 0; j < 8; ++j) { s += mask[base + t * 8 + j]; loc[j] = s; }
    lds[t] = s;
    __syncthreads();
    for (int off = 1; off < 256; off <<= 1) {
        const int v = (t >= off) ? lds[t - off] : 0;
        __syncthreads();
        lds[t] += v;
        __syncthreads();
    }
    const int excl = lds[t] - s;
#pragma unroll
    for (int j = 0; j < 8; ++j) {
        const int e = t * 8 + j;
        const int c = excl + loc[j];
        cid[base + e] = c - 1;
        if (mask[base + e]) bnd[base + c - 1] = e;
    }
    if (t == 255) counts[b] = lds[255];
}

__global__ void smax_k(const int* __restrict__ counts, int* __restrict__ dS)
{
    if (threadIdx.x == 0 && blockIdx.x == 0) {
        int s = counts[0];
        if (counts[1] > s) s = counts[1];
        dS[0] = s;
    }
}

// ---------------- Gather boundary rows of H -> split bf16 (R12: float4) ----
__global__ __launch_bounds__(256)
void gather_k(const float* __restrict__ H, const int* __restrict__ bnd,
              const int* __restrict__ counts, u16* __restrict__ Ghi, u16* __restrict__ Glo)
{
    const int s = blockIdx.x, b = blockIdx.y;
    const int cnt = counts[b];
    const size_t go = ((size_t)b * LSEQ + s) * 768;
    if (s < cnt) {
        const float* h = H + ((size_t)b * LSEQ + bnd[b * LSEQ + s]) * 768;
        for (int d4 = threadIdx.x; d4 < 192; d4 += 256) {
            const float4 v = *(const float4*)(h + d4 * 4);
            u16x4 hv, lv;
            { u16 hh, ll; splitf(v.x, hh, ll); hv[0] = hh; lv[0] = ll; }
            { u16 hh, ll; splitf(v.y, hh, ll); hv[1] = hh; lv[1] = ll; }
            { u16 hh, ll; splitf(v.z, hh, ll); hv[2] = hh; lv[2] = ll; }
            { u16 hh, ll; splitf(v.w, hh, ll); hv[3] = hh; lv[3] = ll; }
            *(u16x4*)(Ghi + go + d4 * 4) = hv;
            *(u16x4*)(Glo + go + d4 * 4) = lv;
        }
    } else {
        const u16x4 z = {0, 0, 0, 0};
        for (int d4 = threadIdx.x; d4 < 192; d4 += 256) {
            *(u16x4*)(Ghi + go + d4 * 4) = z;
            *(u16x4*)(Glo + go + d4 * 4) = z;
        }
    }
}

// ---------------- y = xp[chunk_id] + h (R12: float4) -----------------------
__global__ __launch_bounds__(256)
void ybuild_k(const float* __restrict__ XP, const float* __restrict__ H,
              const int* __restrict__ cid, float* __restrict__ Y)
{
    const int row = blockIdx.x;
    const int b = row >> 11;
    const int c = cid[row];
    const float* xp = XP + ((size_t)b * LSEQ + c) * 768;
    const float* h = H + (size_t)row * 768;
    float* y = Y + (size_t)row * 768;
    for (int d4 = threadIdx.x; d4 < 192; d4 += 256) {
        const float4 a = *(const float4*)(xp + d4 * 4);
        const float4 bb = *(const float4*)(h + d4 * 4);
        float4 o = { a.x + bb.x, a.y + bb.y, a.z + bb.z, a.w + bb.w };
        *(float4*)(y + d4 * 4) = o;
    }
}

// ===========================================================================
extern "C" void kernel_launch(void* const* d_in, const int* in_sizes, int n_in,
                              void* d_out, int out_size, void* d_ws, size_t ws_size,
                              hipStream_t stream)
{
    auto F = [&](int i) { return (const float*)d_in[i]; };

    struct SW { const float *wq, *wk, *wv, *wo, *w1, *w3, *w2, *ln1, *ln2, *nrm; };
    SW comp, proc, dec;
    const float *rw1, *rb1, *rw2, *rb2, *upw, *dnw;

    const bool sig = (in_sizes[11] == 589824);
    if (!sig) {
        comp = { F(1), F(2), F(3), F(4), F(5), F(6), F(7), F(8), F(9), F(10) };
        proc = { F(11), F(12), F(13), F(14), F(15), F(16), F(17), F(18), F(19), F(20) };
        dec  = { F(21), F(22), F(23), F(24), F(25), F(26), F(27), F(28), F(29), F(30) };
        rw1 = F(31); rb1 = F(32); rw2 = F(33); rb2 = F(34); upw = F(35); dnw = F(36);
    } else {
        comp = { F(1), F(2), F(3), F(4), F(5), F(7), F(6), F(8), F(9), F(10) };
        rw1 = F(11); rb1 = F(12); rw2 = F(13); rb2 = F(14); upw = F(15); dnw = F(16);
        proc = { F(17), F(18), F(19), F(20), F(21), F(23), F(22), F(24), F(25), F(26) };
        dec  = { F(27), F(28), F(29), F(30), F(31), F(33), F(32), F(34), F(35), F(36) };
    }

    // ---- workspace carve (aliased for footprint; liveness-verified) ----
    char* ws = (char*)d_ws;
    size_t off = 0;
    auto alloc = [&](size_t bytes) -> void* {
        void* p = ws + off;
        off = (off + bytes + 255) & ~(size_t)255;
        return p;
    };
    float* X    = (float*)alloc(4096ull * 1152 * 4);
    float* BigF = (float*)alloc(4096ull * 6144 * 4);   // QKV | T13(router) | XP (disjoint lifetimes)
    float* HC   = (float*)alloc(4096ull * 768 * 4);
    u16* HNhi   = (u16*)alloc(4096ull * 1152 * 2);     // also HC-split + gather G
    u16* HNlo   = (u16*)alloc(4096ull * 1152 * 2);
    u16* SWhi   = (u16*)alloc(4096ull * 3072 * 2);     // also attention O (disjoint)
    u16* SWlo   = (u16*)alloc(4096ull * 3072 * 2);
    u16* Khi    = (u16*)alloc(24ull * 2048 * 96 * 2);
    u16* Klo    = (u16*)alloc(24ull * 2048 * 96 * 2);
    u16* Vthi   = (u16*)alloc(24ull * 2048 * 96 * 2);
    u16* Vtlo   = (u16*)alloc(24ull * 2048 * 96 * 2);
    float* Pacc = (float*)alloc(24ull * 72 * 64 * 96 * 4);   // k-chunk partials (72 slots/bh)
    float* Pml  = (float*)alloc(24ull * 72 * 64 * 2 * 4);
    u16* qkvPhi = (u16*)alloc(3981312ull * 2);
    u16* qkvPlo = (u16*)alloc(3981312ull * 2);
    u16* woPhi  = (u16*)alloc(1327104ull * 2);
    u16* woPlo  = (u16*)alloc(1327104ull * 2);
    u16* w13Phi = (u16*)alloc(7077888ull * 2);
    u16* w13Plo = (u16*)alloc(7077888ull * 2);
    u16* w2Phi  = (u16*)alloc(3538944ull * 2);
    u16* w2Plo  = (u16*)alloc(3538944ull * 2);
    u16* rw1Phi = (u16*)alloc(589824ull * 2);
    u16* rw1Plo = (u16*)alloc(589824ull * 2);
    u16* upwPhi = (u16*)alloc(884736ull * 2);
    u16* upwPlo = (u16*)alloc(884736ull * 2);
    u16* dnwPhi = (u16*)alloc(884736ull * 2);
    u16* dnwPlo = (u16*)alloc(884736ull * 2);
    int* mask   = (int*)alloc(4096 * 4);
    int* cid    = (int*)alloc(4096 * 4);
    int* bnd    = (int*)alloc(4096 * 4);
    int* cnts   = (int*)alloc(2 * 4);
    int* dS     = (int*)alloc(256);
    float* c1   = (float*)alloc(2048ull * 32 * 4);
    float* s1   = (float*)alloc(2048ull * 32 * 4);
    float* c2   = (float*)alloc(2048ull * 48 * 4);
    float* s2   = (float*)alloc(2048ull * 48 * 4);

    float* QKV = BigF;              // lives: qkv-gemm .. fattn2
    float* T13 = BigF;              // lives: router gemm only
    float* XP  = BigF;              // lives: down-gemm .. ybuild
    u16* Ohi = SWhi;                // lives: fattn2 .. wo-gemm
    u16* Olo = SWlo;

    hipMemcpyAsync(X, F(0), 4096ull * 768 * 4, hipMemcpyDeviceToDevice, stream);
    ropetab_k<<<640, 256, 0, stream>>>(c1, s1, c2, s2);

    // ---- split router/up/down once ----
    {
        SplitArgs sa{};
        sa.ne = 3;
        sa.e[0] = { rw1, nullptr, nullptr, rw1Phi, rw1Plo, 768, 768, 1, 0, 0 };
        sa.e[1] = { upw, nullptr, nullptr, upwPhi, upwPlo, 768, 1152, 1, 288, 0 };
        sa.e[2] = { dnw, nullptr, nullptr, dnwPhi, dnwPlo, 1152, 768, 1, 720, 0 };
        wsplit_k<<<1152, 256, 0, stream>>>(sa);
    }

    // BM=64 everywhere (R10): 48KB LDS -> 3 blocks/CU, 2x block count.
    auto gemm = [&](const u16* ahi, const u16* alo, const u16* bhi, const u16* blo,
                    const float* res, float* c, int N, int K, const int* ds) {
        if (ds) gemm_mfma_k<true, false, 64><<<dim3(N / 128, 64), 256, 0, stream>>>(
                    ahi, alo, bhi, blo, res, c, nullptr, nullptr, N, K, ds);
        else    gemm_mfma_k<false, false, 64><<<dim3(N / 128, 64), 256, 0, stream>>>(
                    ahi, alo, bhi, blo, res, c, nullptr, nullptr, N, K, nullptr);
    };
    auto gemmswi = [&](const u16* ahi, const u16* alo, const u16* bhi, const u16* blo,
                       u16* shi, u16* slo, int N, int K, const int* ds) {
        if (ds) gemm_mfma_k<true, true, 64><<<dim3(N / 128, 64), 256, 0, stream>>>(
                    ahi, alo, bhi, blo, nullptr, nullptr, shi, slo, N, K, ds);
        else    gemm_mfma_k<false, true, 64><<<dim3(N / 128, 64), 256, 0, stream>>>(
                    ahi, alo, bhi, blo, nullptr, nullptr, shi, slo, N, K, nullptr);
    };

    auto run_layer = [&](const SW& W, int li, int dm, int ff, int hd,
                         const float* ct, const float* st, const int* ds) {
        const size_t wsz = (size_t)dm * dm;
        const float* wq = W.wq + (size_t)li * wsz;
        const float* wk = W.wk + (size_t)li * wsz;
        const float* wv = W.wv + (size_t)li * wsz;
        const float* wo = W.wo + (size_t)li * wsz;
        const float* w1 = W.w1 + (size_t)li * dm * ff;
        const float* w3 = W.w3 + (size_t)li * dm * ff;
        const float* w2 = W.w2 + (size_t)li * ff * dm;
        const float* ln1 = W.ln1 + (size_t)li * dm;
        const float* ln2 = W.ln2 + (size_t)li * dm;
        const float scale = 1.0f / sqrtf((float)hd);

        // pack this layer's weights (w1/w3 column-interleaved for fused swiglu)
        {
            const int b0 = dm * 3 * dm / 2048, b1 = dm * dm / 2048, b2 = dm * 2 * ff / 2048,
                      b3 = ff * dm / 2048;
            SplitArgs sa{};
            sa.ne = 4;
            sa.e[0] = { wq, wk, wv, qkvPhi, qkvPlo, dm, dm, 3, 0, 0 };
            sa.e[1] = { wo, nullptr, nullptr, woPhi, woPlo, dm, dm, 1, b0, 0 };
            sa.e[2] = { w1, w3, nullptr, w13Phi, w13Plo, dm, ff, 2, b0 + b1, 1 };
            sa.e[3] = { w2, nullptr, nullptr, w2Phi, w2Plo, ff, dm, 1, b0 + b1 + b2, 0 };
            wsplit_k<<<b0 + b1 + b2 + b3, 256, 0, stream>>>(sa);
        }

        rmsnorm_k<false, true><<<4096, 256, 0, stream>>>(X, ln1, nullptr, HNhi, HNlo, dm, ds);
        gemm(HNhi, HNlo, qkvPhi, qkvPlo, nullptr, QKV, 3 * dm, dm, ds);
        if (hd == 64) {
            prep_k<64><<<768, 256, 0, stream>>>(QKV, Khi, Klo, Vthi, Vtlo, ct, st, dm, ds);
            fattn2_k<64><<<1920, 256, 0, stream>>>(QKV, Khi, Klo, Vthi, Vtlo, Ohi, Olo, Pacc, Pml, dm, scale, ds);
            attn_merge_k<64><<<576, 256, 0, stream>>>(Pacc, Pml, Ohi, Olo, dm, ds);
        } else {
            prep_k<96><<<768, 256, 0, stream>>>(QKV, Khi, Klo, Vthi, Vtlo, ct, st, dm, ds);
            fattn2_k<96><<<1920, 256, 0, stream>>>(QKV, Khi, Klo, Vthi, Vtlo, Ohi, Olo, Pacc, Pml, dm, scale, ds);
            attn_merge_k<96><<<576, 256, 0, stream>>>(Pacc, Pml, Ohi, Olo, dm, ds);
        }
        gemm(Ohi, Olo, woPhi, woPlo, X, X, dm, dm, ds);
        rmsnorm_k<false, true><<<4096, 256, 0, stream>>>(X, ln2, nullptr, HNhi, HNlo, dm, ds);
        gemmswi(HNhi, HNlo, w13Phi, w13Plo, SWhi, SWlo, 2 * ff, dm, ds);
        gemm(SWhi, SWlo, w2Phi, w2Plo, X, X, dm, ff, ds);
    };

    // ---- compressor trunk (dense) ----
    for (int i = 0; i < 3; ++i) run_layer(comp, i, 768, 2048, 64, c1, s1, nullptr);
    rmsnorm_k<true, true><<<4096, 256, 0, stream>>>(X, comp.nrm, HC, HNhi, HNlo, 768, nullptr);

    // ---- router (HNhi/HNlo hold split HC here) ----
    gemm(HNhi, HNlo, rw1Phi, rw1Plo, nullptr, T13, 768, 768, nullptr);
    router2_k<<<4096, 256, 0, stream>>>(T13, rb1, rw2, rb2, mask);
    scan_k<<<2, 256, 0, stream>>>(mask, cid, bnd, cnts);
    smax_k<<<1, 64, 0, stream>>>(cnts, dS);

    // ---- gather (reuses HNhi/HNlo as G) + up-projection ----
    gather_k<<<dim3(LSEQ, 2), 256, 0, stream>>>(HC, bnd, cnts, HNhi, HNlo);
    gemm(HNhi, HNlo, upwPhi, upwPlo, nullptr, X, 1152, 768, dS);

    // ---- processor stack (padded) ----
    for (int i = 0; i < 6; ++i) run_layer(proc, i, 1152, 3072, 96, c2, s2, dS);
    rmsnorm_k<false, true><<<4096, 256, 0, stream>>>(X, proc.nrm, nullptr, HNhi, HNlo, 1152, dS);
    gemm(HNhi, HNlo, dnwPhi, dnwPlo, nullptr, XP, 768, 1152, dS);

    // ---- scatter back + decoder (dense) ----
    ybuild_k<<<4096, 256, 0, stream>>>(XP, HC, cid, X);
    for (int i = 0; i < 3; ++i) run_layer(dec, i, 768, 2048, 64, c1, s1, nullptr);
    rmsnorm_k<true, false><<<4096, 256, 0, stream>>>(X, dec.nrm, (float*)d_out, nullptr, nullptr, 768, nullptr);
}